// Round 1
// baseline (1905.704 us; speedup 1.0000x reference)
//
#include <hip/hip_runtime.h>
#include <math.h>

#ifndef M_PI_F
#define M_PI_F 3.14159265358979323846f
#endif

static constexpr int Bb = 2, Tt = 1024, Dd = 1024, Hh = 16, DHh = 64, NFf = 256, Rr = 4096;
static constexpr int Mm = Bb * Tt;

enum Epi { EPI_NONE = 0, EPI_RELU, EPI_SOFTPLUS, EPI_TANHPI };

// ---------------------------------------------------------------------------
// Generic fp32 tiled GEMM: C[M,N] = epi(A[M,K] @ B[K,N] + bias)
// 64x64 tile, K-step 16, 256 threads, 4x4 micro-tile per thread.
// LDS rows padded to 68 floats (272B) so float4 LDS reads stay 16B-aligned.
// Assumes M%64==0, N%64==0, K%16==0 (true for all shapes here).
// ---------------------------------------------------------------------------
template <int EPI>
__global__ __launch_bounds__(256) void gemm_f32(const float* __restrict__ A,
                                                const float* __restrict__ B,
                                                const float* __restrict__ bias,
                                                float* __restrict__ C,
                                                int M, int N, int K) {
  __shared__ float As[16][68];
  __shared__ float Bs[16][68];
  const int tid = threadIdx.x;
  const int bn = blockIdx.x, bm = blockIdx.y;
  const int tx = tid & 15, ty = tid >> 4;
  const int row0 = bm * 64, col0 = bn * 64;
  const int a_m = tid >> 2, a_k = (tid & 3) << 2;   // A: 64 rows x 16 k, float4 per thread
  const int b_k = tid >> 4, b_n = (tid & 15) << 2;  // B: 16 k x 64 cols, float4 per thread
  const float* Ap = A + (size_t)(row0 + a_m) * K + a_k;
  const float* Bp = B + (size_t)b_k * N + (col0 + b_n);
  float acc[4][4] = {};
  for (int k0 = 0; k0 < K; k0 += 16) {
    const float4 av = *reinterpret_cast<const float4*>(Ap + k0);
    const float4 bv = *reinterpret_cast<const float4*>(Bp + (size_t)k0 * N);
    As[a_k + 0][a_m] = av.x;
    As[a_k + 1][a_m] = av.y;
    As[a_k + 2][a_m] = av.z;
    As[a_k + 3][a_m] = av.w;
    *reinterpret_cast<float4*>(&Bs[b_k][b_n]) = bv;
    __syncthreads();
#pragma unroll
    for (int kk = 0; kk < 16; ++kk) {
      const float4 a4 = *reinterpret_cast<const float4*>(&As[kk][ty << 2]);
      const float4 b4 = *reinterpret_cast<const float4*>(&Bs[kk][tx << 2]);
      const float ar[4] = {a4.x, a4.y, a4.z, a4.w};
      const float br[4] = {b4.x, b4.y, b4.z, b4.w};
#pragma unroll
      for (int i = 0; i < 4; ++i)
#pragma unroll
        for (int j = 0; j < 4; ++j) acc[i][j] = fmaf(ar[i], br[j], acc[i][j]);
    }
    __syncthreads();
  }
  float bvals[4] = {0.f, 0.f, 0.f, 0.f};
  if (bias) {
#pragma unroll
    for (int j = 0; j < 4; ++j) bvals[j] = bias[col0 + (tx << 2) + j];
  }
#pragma unroll
  for (int i = 0; i < 4; ++i) {
    float4 o4;
    float* op = &o4.x;
#pragma unroll
    for (int j = 0; j < 4; ++j) {
      float val = acc[i][j] + bvals[j];
      if (EPI == EPI_RELU) {
        val = fmaxf(val, 0.f);
      } else if (EPI == EPI_SOFTPLUS) {
        val = (val > 0.f) ? (val + log1pf(expf(-val))) : log1pf(expf(val));
      } else if (EPI == EPI_TANHPI) {
        val = M_PI_F * tanhf(val);
      }
      op[j] = val;
    }
    *reinterpret_cast<float4*>(&C[(size_t)(row0 + (ty << 2) + i) * N + col0 + (tx << 2)]) = o4;
  }
}

// ---------------------------------------------------------------------------
// Sequential complex resonator recurrence. One thread per (b, f).
// Writes feat = [Re X, Im X, |X|] with layout [B, T, 3*NF].
// ---------------------------------------------------------------------------
__global__ __launch_bounds__(256) void resonator_scan(const float* __restrict__ amp,
                                                      const float* __restrict__ phi,
                                                      const float* __restrict__ omega,
                                                      const float* __restrict__ ret_logit,
                                                      const float* __restrict__ theta,
                                                      float* __restrict__ feat) {
  const int f = threadIdx.x;  // NF = 256
  const int b = blockIdx.x;   // B
  const float dec = 1.f / (1.f + expf(-ret_logit[f]));
  float so, co;
  sincosf(omega[f], &so, &co);
  const float ar = dec * co, ai = dec * so;
  const float th = theta[f];
  float Xr = 0.f, Xi = 0.f;
  for (int t = 0; t < Tt; ++t) {
    const size_t idx = ((size_t)b * Tt + t) * NFf + f;
    const float am = amp[idx], ph = phi[idx];
    float sp, cp;
    sincosf(ph, &sp, &cp);
    const float ur = am * cp, ui = am * sp;
    const float pr = fmaf(ar, Xr, fmaf(-ai, Xi, ur));
    const float pim = fmaf(ar, Xi, fmaf(ai, Xr, ui));
    const float mag = sqrtf(fmaf(pr, pr, pim * pim));
    const float g = 1.f / (1.f + expf(-(mag - th)));
    Xr = pr * g;
    Xi = pim * g;
    const size_t fb = ((size_t)b * Tt + t) * (3 * NFf);
    feat[fb + f] = Xr;
    feat[fb + NFf + f] = Xi;
    feat[fb + 2 * NFf + f] = mag * g;  // |pre*g| = |pre|*g since g>=0
  }
}

// ---------------------------------------------------------------------------
// Causal linear attention, sequential cumulative state per (b,h).
// 256 threads: thread (eg = tid>>2, dg = tid&3) owns kv[d, eg] for
// d in [dg*16, dg*16+16). Reductions over the d-dim via __shfl_xor(1|2).
// Stages 16 timesteps of q,k,v in LDS per chunk.
// ---------------------------------------------------------------------------
__global__ __launch_bounds__(256) void attn_scan(const float* __restrict__ q,
                                                 const float* __restrict__ k,
                                                 const float* __restrict__ v,
                                                 float* __restrict__ y) {
  __shared__ float ks[16][64], vs[16][64], qs[16][64];
  const int bh = blockIdx.x;
  const int b = bh >> 4, h = bh & 15;
  const int tid = threadIdx.x;
  const int eg = tid >> 2, dg = tid & 3;
  float kv[16] = {};
  float ksum[16] = {};
  const size_t base = ((size_t)b * Tt * Hh + h) * DHh;
  const size_t step = (size_t)Hh * DHh;
  for (int t0 = 0; t0 < Tt; t0 += 16) {
    for (int l = tid; l < 16 * 192; l += 256) {
      const int s = l / 192, r = l % 192;
      const int wh = r >> 6, d = r & 63;
      const size_t g = base + (size_t)(t0 + s) * step + d;
      if (wh == 0)
        ks[s][d] = k[g];
      else if (wh == 1)
        vs[s][d] = v[g];
      else
        qs[s][d] = q[g];
    }
    __syncthreads();
    for (int s = 0; s < 16; ++s) {
      float kr[16], qr[16];
#pragma unroll
      for (int c = 0; c < 4; ++c) {
        *reinterpret_cast<float4*>(&kr[c * 4]) =
            *reinterpret_cast<const float4*>(&ks[s][dg * 16 + c * 4]);
        *reinterpret_cast<float4*>(&qr[c * 4]) =
            *reinterpret_cast<const float4*>(&qs[s][dg * 16 + c * 4]);
      }
      const float ve = vs[s][eg];
      float pn = 0.f, pd = 0.f;
#pragma unroll
      for (int i = 0; i < 16; ++i) {
        kv[i] = fmaf(kr[i], ve, kv[i]);
        ksum[i] += kr[i];
        pn = fmaf(qr[i], kv[i], pn);
        pd = fmaf(qr[i], ksum[i], pd);
      }
      pn += __shfl_xor(pn, 1);
      pn += __shfl_xor(pn, 2);
      pd += __shfl_xor(pd, 1);
      pd += __shfl_xor(pd, 2);
      if (dg == 0) y[base + (size_t)(t0 + s) * step + eg] = pn / (pd + 1e-6f);
    }
    __syncthreads();
  }
}

// ---------------------------------------------------------------------------
// Per-head layernorm over DH=64. One wave per (b,t,h) row; 4 rows per block.
// ---------------------------------------------------------------------------
__global__ __launch_bounds__(256) void ln_head(const float* __restrict__ y,
                                               const float* __restrict__ w,
                                               const float* __restrict__ bsh,
                                               float* __restrict__ out) {
  const int tid = threadIdx.x;
  const int e = tid & 63;
  const int r = blockIdx.x * 4 + (tid >> 6);  // row in [0, B*T*H)
  const int h = r & (Hh - 1);
  const float val = y[(size_t)r * DHh + e];
  float s = val;
#pragma unroll
  for (int o = 1; o < 64; o <<= 1) s += __shfl_xor(s, o);
  const float mean = s * (1.f / 64.f);
  const float dv = val - mean;
  float s2 = dv * dv;
#pragma unroll
  for (int o = 1; o < 64; o <<= 1) s2 += __shfl_xor(s2, o);
  const float var = s2 * (1.f / 64.f);
  out[(size_t)r * DHh + e] = dv * rsqrtf(var + 1e-5f) * w[h * DHh + e] + bsh[h * DHh + e];
}

// ---------------------------------------------------------------------------
// Residual + final layernorm over D=1024. One block per (b,t) row.
// ---------------------------------------------------------------------------
__global__ __launch_bounds__(256) void final_ln(const float* __restrict__ x,
                                                const float* __restrict__ f2,
                                                const float* __restrict__ w,
                                                const float* __restrict__ bb,
                                                float* __restrict__ out) {
  __shared__ float r1[4], r2[4];
  const int row = blockIdx.x;
  const int tid = threadIdx.x;
  const size_t off = (size_t)row * Dd + tid * 4;
  const float4 xa = *reinterpret_cast<const float4*>(&x[off]);
  const float4 fa = *reinterpret_cast<const float4*>(&f2[off]);
  float z[4] = {xa.x + fa.x, xa.y + fa.y, xa.z + fa.z, xa.w + fa.w};
  float s1 = z[0] + z[1] + z[2] + z[3];
  float s2 = z[0] * z[0] + z[1] * z[1] + z[2] * z[2] + z[3] * z[3];
#pragma unroll
  for (int o = 1; o < 64; o <<= 1) {
    s1 += __shfl_xor(s1, o);
    s2 += __shfl_xor(s2, o);
  }
  const int wid = tid >> 6;
  if ((tid & 63) == 0) {
    r1[wid] = s1;
    r2[wid] = s2;
  }
  __syncthreads();
  const float t1 = r1[0] + r1[1] + r1[2] + r1[3];
  const float t2 = r2[0] + r2[1] + r2[2] + r2[3];
  const float mu = t1 * (1.f / Dd);
  const float var = t2 * (1.f / Dd) - mu * mu;
  const float rs = rsqrtf(var + 1e-5f);
  float4 o4;
  float* op = &o4.x;
#pragma unroll
  for (int j = 0; j < 4; ++j) op[j] = (z[j] - mu) * rs * w[tid * 4 + j] + bb[tid * 4 + j];
  *reinterpret_cast<float4*>(&out[off]) = o4;
}

// ---------------------------------------------------------------------------
extern "C" void kernel_launch(void* const* d_in, const int* in_sizes, int n_in,
                              void* d_out, int out_size, void* d_ws, size_t ws_size,
                              hipStream_t stream) {
  const float* x = (const float*)d_in[0];
  const float* W_amp = (const float*)d_in[1];
  const float* b_amp = (const float*)d_in[2];
  const float* W_phi = (const float*)d_in[3];
  const float* b_phi = (const float*)d_in[4];
  const float* omega = (const float*)d_in[5];
  const float* ret_logit = (const float*)d_in[6];
  const float* theta = (const float*)d_in[7];
  const float* W_feat = (const float*)d_in[8];
  const float* b_feat = (const float*)d_in[9];
  const float* Wq = (const float*)d_in[10];
  const float* Wk = (const float*)d_in[11];
  const float* Wv = (const float*)d_in[12];
  const float* lnh_w = (const float*)d_in[13];
  const float* lnh_b = (const float*)d_in[14];
  const float* W1 = (const float*)d_in[15];
  const float* b1 = (const float*)d_in[16];
  const float* W2 = (const float*)d_in[17];
  const float* b2 = (const float*)d_in[18];
  const float* ln_w = (const float*)d_in[19];
  const float* ln_b = (const float*)d_in[20];

  // Workspace layout (fp32 elements). Peak = 13,107,200 floats = 52.4 MB.
  float* ws = (float*)d_ws;
  float* amp = ws + 0;         //  512K  [B,T,NF]
  float* phi = ws + 524288;    //  512K  [B,T,NF]
  float* feat = ws + 1048576;  // 1.5M   [B,T,3NF]
  float* h = ws + 2621440;     //   2M   [B,T,D]
  float* q = ws + 4718592;     //   2M   [B,T,H,DH]
  float* k = ws + 6815744;     //   2M
  float* v = ws + 8912896;     //   2M
  float* y = ws + 11010048;    //   2M
  float* yh = h;               // reuse: h is dead after q/k/v GEMMs
  float* f1 = q;               // reuse: spans q..y (8M floats), dead after attn+LN
  float* f2 = amp;             // reuse: amp/phi/feat dead
  float* out = (float*)d_out;

  const dim3 blk(256);
  // 1-2: resonator input projections with fused activations
  gemm_f32<EPI_SOFTPLUS><<<dim3(NFf / 64, Mm / 64), blk, 0, stream>>>(x, W_amp, b_amp, amp, Mm, NFf, Dd);
  gemm_f32<EPI_TANHPI><<<dim3(NFf / 64, Mm / 64), blk, 0, stream>>>(x, W_phi, b_phi, phi, Mm, NFf, Dd);
  // 3: sequential resonator recurrence -> feat
  resonator_scan<<<dim3(Bb), blk, 0, stream>>>(amp, phi, omega, ret_logit, theta, feat);
  // 4: feat projection
  gemm_f32<EPI_RELU><<<dim3(Dd / 64, Mm / 64), blk, 0, stream>>>(feat, W_feat, b_feat, h, Mm, Dd, 3 * NFf);
  // 5-7: q,k,v projections (no bias; q,k relu'd)
  gemm_f32<EPI_RELU><<<dim3(Dd / 64, Mm / 64), blk, 0, stream>>>(h, Wq, nullptr, q, Mm, Dd, Dd);
  gemm_f32<EPI_RELU><<<dim3(Dd / 64, Mm / 64), blk, 0, stream>>>(h, Wk, nullptr, k, Mm, Dd, Dd);
  gemm_f32<EPI_NONE><<<dim3(Dd / 64, Mm / 64), blk, 0, stream>>>(h, Wv, nullptr, v, Mm, Dd, Dd);
  // 8: causal linear attention scan
  attn_scan<<<dim3(Bb * Hh), blk, 0, stream>>>(q, k, v, y);
  // 9: per-head layernorm
  ln_head<<<dim3(Bb * Tt * Hh / 4), blk, 0, stream>>>(y, lnh_w, lnh_b, yh);
  // 10-11: low-rank FFN (positive_out)
  gemm_f32<EPI_RELU><<<dim3(Rr / 64, Mm / 64), blk, 0, stream>>>(yh, W1, b1, f1, Mm, Rr, Dd);
  gemm_f32<EPI_RELU><<<dim3(Dd / 64, Mm / 64), blk, 0, stream>>>(f1, W2, b2, f2, Mm, Dd, Rr);
  // 12: residual + final layernorm
  final_ln<<<dim3(Mm), blk, 0, stream>>>(x, f2, ln_w, ln_b, out);
}

// Round 2
// 639.758 us; speedup vs baseline: 2.9788x; 2.9788x over previous
//
#include <hip/hip_runtime.h>
#include <hip/hip_bf16.h>
#include <math.h>

#ifndef M_PI_F
#define M_PI_F 3.14159265358979323846f
#endif

static constexpr int Bb = 2, Tt = 1024, Dd = 1024, Hh = 16, DHh = 64, NFf = 256, Rr = 4096;
static constexpr int Mm = Bb * Tt;
static constexpr int CHK = 64, NCHK = Tt / CHK;  // attention chunking

enum Epi { EPI_NONE = 0, EPI_RELU, EPI_SOFTPLUS, EPI_TANHPI };

typedef __attribute__((ext_vector_type(8))) short bf16x8;
typedef __attribute__((ext_vector_type(4))) float f32x4;

// ---------------------------------------------------------------------------
// async global->LDS, 16B per lane. LDS dest is wave-uniform base; HW adds
// lane*16. Global address is per-lane.
// ---------------------------------------------------------------------------
__device__ inline void gload16(const short* g, short* l) {
  __builtin_amdgcn_global_load_lds(
      (const __attribute__((address_space(1))) unsigned int*)g,
      (__attribute__((address_space(3))) unsigned int*)l, 16, 0, 0);
}

// ---------------------------------------------------------------------------
// bf16 MFMA GEMM: C[M,N] = epi(A[M,K] @ BT[N,K]^T + bias)
// 128x128 tile, BK=64, 4 waves (2x2), each wave 64x64 via 4x4 frags of
// 16x16x32 MFMA. Single-buffer 2-barrier K-loop (m97 structure).
// ---------------------------------------------------------------------------
template <int EPI, int OUTBF>
__global__ __launch_bounds__(256) void gemm_mfma(const short* __restrict__ A,
                                                 const short* __restrict__ BT,
                                                 const float* __restrict__ bias,
                                                 float* __restrict__ Cf,
                                                 __hip_bfloat16* __restrict__ Cb,
                                                 int M, int N, int K) {
  __shared__ short lA[128 * 64];
  __shared__ short lB[128 * 64];
  const int tid = threadIdx.x;
  const int wid = tid >> 6, lane = tid & 63;
  const int m0 = blockIdx.y * 128, n0 = blockIdx.x * 128;
  const int wm = (wid >> 1) * 64, wn = (wid & 1) * 64;
  const int srow = lane >> 3;          // row within 8-row stage slab
  const int skk = (lane & 7) * 8;      // k offset (elements)

  f32x4 acc[4][4] = {};

  for (int k0 = 0; k0 < K; k0 += 64) {
#pragma unroll
    for (int si = 0; si < 4; ++si) {
      const int s = wid + si * 4;  // stage instruction index 0..15
      gload16(A + (size_t)(m0 + s * 8 + srow) * K + k0 + skk, &lA[s * 512]);
      gload16(BT + (size_t)(n0 + s * 8 + srow) * K + k0 + skk, &lB[s * 512]);
    }
    __syncthreads();  // drains vmcnt -> LDS tiles ready
#pragma unroll
    for (int kk = 0; kk < 2; ++kk) {
      const int krd = kk * 32 + (lane >> 4) * 8;
      const int rsel = lane & 15;
      bf16x8 af[4], bfr[4];
#pragma unroll
      for (int i = 0; i < 4; ++i) {
        af[i] = *(const bf16x8*)&lA[(wm + i * 16 + rsel) * 64 + krd];
        bfr[i] = *(const bf16x8*)&lB[(wn + i * 16 + rsel) * 64 + krd];
      }
#pragma unroll
      for (int i = 0; i < 4; ++i)
#pragma unroll
        for (int j = 0; j < 4; ++j)
          acc[i][j] = __builtin_amdgcn_mfma_f32_16x16x32_bf16(af[i], bfr[j], acc[i][j], 0, 0, 0);
    }
    __syncthreads();  // compute done before restage
  }

  const int crow = (lane >> 4) * 4;
  const int ccol = lane & 15;
#pragma unroll
  for (int j = 0; j < 4; ++j) {
    const int col = n0 + wn + j * 16 + ccol;
    const float bv = bias ? bias[col] : 0.f;
#pragma unroll
    for (int i = 0; i < 4; ++i) {
#pragma unroll
      for (int r = 0; r < 4; ++r) {
        float v = acc[i][j][r] + bv;
        if (EPI == EPI_RELU) {
          v = fmaxf(v, 0.f);
        } else if (EPI == EPI_SOFTPLUS) {
          v = (v > 0.f) ? (v + log1pf(expf(-v))) : log1pf(expf(v));
        } else if (EPI == EPI_TANHPI) {
          v = M_PI_F * tanhf(v);
        }
        const size_t off = (size_t)(m0 + wm + i * 16 + crow + r) * N + col;
        if (OUTBF)
          Cb[off] = __float2bfloat16(v);
        else
          Cf[off] = v;
      }
    }
  }
}

// ---------------------------------------------------------------------------
// Fused transpose-cast of all 8 weight matrices: W[K,N] f32 -> WT[N,K] bf16.
// ---------------------------------------------------------------------------
struct TCDesc {
  const float* src[8];
  __hip_bfloat16* dst[8];
};

__global__ __launch_bounds__(256) void transpose_cast_all(TCDesc d) {
  constexpr int KS[8] = {1024, 1024, 768, 1024, 1024, 1024, 1024, 4096};
  constexpr int NS[8] = {256, 256, 1024, 1024, 1024, 1024, 4096, 1024};
  constexpr int CUM[9] = {0, 256, 512, 1280, 2304, 3328, 4352, 8448, 12544};
  __shared__ float tile[32][33];
  const int bid = blockIdx.x;
  int w = 0;
#pragma unroll
  for (int i = 0; i < 8; ++i)
    if (bid >= CUM[i + 1]) w = i + 1;
  const int tlocal = bid - CUM[w];
  const int K = KS[w], N = NS[w];
  const int tilesN = N / 32;
  const int bk = (tlocal / tilesN) * 32, bn = (tlocal % tilesN) * 32;
  const float* W = d.src[w];
  __hip_bfloat16* WT = d.dst[w];
  const int tx = threadIdx.x & 31, ty = threadIdx.x >> 5;  // 32x8
#pragma unroll
  for (int r = 0; r < 32; r += 8) tile[ty + r][tx] = W[(size_t)(bk + ty + r) * N + bn + tx];
  __syncthreads();
#pragma unroll
  for (int r = 0; r < 32; r += 8)
    WT[(size_t)(bn + ty + r) * K + bk + tx] = __float2bfloat16(tile[tx][ty + r]);
}

// ---------------------------------------------------------------------------
// x: f32 -> bf16 cast (row-major, layout preserved)
// ---------------------------------------------------------------------------
__global__ __launch_bounds__(256) void cast_x(const float* __restrict__ x,
                                              __hip_bfloat16* __restrict__ xb) {
  const int i = (blockIdx.x * 256 + threadIdx.x) * 4;
  const float4 v = *(const float4*)&x[i];
  xb[i + 0] = __float2bfloat16(v.x);
  xb[i + 1] = __float2bfloat16(v.y);
  xb[i + 2] = __float2bfloat16(v.z);
  xb[i + 3] = __float2bfloat16(v.w);
}

// ---------------------------------------------------------------------------
// polar -> cartesian in place: (amp, phi) -> (amp*cos(phi), amp*sin(phi))
// ---------------------------------------------------------------------------
__global__ __launch_bounds__(256) void polar_kernel(float* __restrict__ a,
                                                    float* __restrict__ p) {
  const int i = blockIdx.x * 256 + threadIdx.x;
  const float am = a[i], ph = p[i];
  float s, c;
  sincosf(ph, &s, &c);
  a[i] = am * c;
  p[i] = am * s;
}

// ---------------------------------------------------------------------------
// Sequential complex resonator recurrence; writes feat bf16 [B,T,3*NF].
// ---------------------------------------------------------------------------
__global__ __launch_bounds__(256) void resonator_scan(const float* __restrict__ ur,
                                                      const float* __restrict__ ui,
                                                      const float* __restrict__ omega,
                                                      const float* __restrict__ ret_logit,
                                                      const float* __restrict__ theta,
                                                      __hip_bfloat16* __restrict__ featb) {
  const int f = threadIdx.x;
  const int b = blockIdx.x;
  const float dec = 1.f / (1.f + __expf(-ret_logit[f]));
  float so, co;
  sincosf(omega[f], &so, &co);
  const float ar = dec * co, ai = dec * so;
  const float th = theta[f];
  float Xr = 0.f, Xi = 0.f;
  for (int t = 0; t < Tt; ++t) {
    const size_t idx = ((size_t)b * Tt + t) * NFf + f;
    const float pr = fmaf(ar, Xr, fmaf(-ai, Xi, ur[idx]));
    const float pim = fmaf(ar, Xi, fmaf(ai, Xr, ui[idx]));
    const float mag = sqrtf(fmaf(pr, pr, pim * pim));
    const float g = 1.f / (1.f + __expf(th - mag));
    Xr = pr * g;
    Xi = pim * g;
    const size_t fb = ((size_t)b * Tt + t) * (3 * NFf);
    featb[fb + f] = __float2bfloat16(Xr);
    featb[fb + NFf + f] = __float2bfloat16(Xi);
    featb[fb + 2 * NFf + f] = __float2bfloat16(mag * g);
  }
}

// ---------------------------------------------------------------------------
// Attention phase A: per-chunk KV outer-product sums and k-sums.
// grid = B*H*NCHK; S[g][d][e] (64x64), Ksum[g][d].
// ---------------------------------------------------------------------------
__global__ __launch_bounds__(256) void attn_chunk_kv(const float* __restrict__ k,
                                                     const float* __restrict__ v,
                                                     float* __restrict__ S,
                                                     float* __restrict__ Ksum) {
  __shared__ float Ks[64][68], Vs[64][68];
  const int g = blockIdx.x;
  const int j = g & (NCHK - 1), bh = g >> 4;
  const int b = bh >> 4, h = bh & (Hh - 1);
  const int tid = threadIdx.x;
  const size_t rowbase = (((size_t)b * Tt + j * CHK) * Hh + h) * DHh;
  const size_t rstep = (size_t)Hh * DHh;
  for (int l = tid; l < 4096; l += 256) {
    const int s = l >> 6, d = l & 63;
    Ks[s][d] = k[rowbase + s * rstep + d];
    Vs[s][d] = v[rowbase + s * rstep + d];
  }
  __syncthreads();
  const int d0 = tid & 63, eb = tid >> 6, e0 = eb * 16;
  float4 acc4[4] = {};
  float ks = 0.f;
  for (int s = 0; s < 64; ++s) {
    const float kd = Ks[s][d0];
    ks += kd;
#pragma unroll
    for (int i = 0; i < 4; ++i) {
      const float4 v4 = *(const float4*)&Vs[s][e0 + 4 * i];
      acc4[i].x = fmaf(kd, v4.x, acc4[i].x);
      acc4[i].y = fmaf(kd, v4.y, acc4[i].y);
      acc4[i].z = fmaf(kd, v4.z, acc4[i].z);
      acc4[i].w = fmaf(kd, v4.w, acc4[i].w);
    }
  }
  float* Sg = S + (size_t)g * 4096 + (size_t)d0 * 64 + e0;
#pragma unroll
  for (int i = 0; i < 4; ++i) *(float4*)&Sg[4 * i] = acc4[i];
  if (eb == 0) Ksum[(size_t)g * 64 + d0] = ks;
}

// ---------------------------------------------------------------------------
// Attention phase B: in-place EXCLUSIVE prefix over the 16 chunks per (b,h).
// ---------------------------------------------------------------------------
__global__ __launch_bounds__(256) void attn_prefix(float* __restrict__ S,
                                                   float* __restrict__ Ksum) {
  const int bh = blockIdx.x;
  const int tid = threadIdx.x;
  for (int r = 0; r < 16; ++r) {
    const int de = r * 256 + tid;
    float run = 0.f;
    size_t p = (size_t)bh * (NCHK * 4096) + de;
    for (int j = 0; j < NCHK; ++j, p += 4096) {
      const float tmp = S[p];
      S[p] = run;
      run += tmp;
    }
  }
  if (tid < 64) {
    float run = 0.f;
    size_t p = (size_t)bh * (NCHK * 64) + tid;
    for (int j = 0; j < NCHK; ++j, p += 64) {
      const float tmp = Ksum[p];
      Ksum[p] = run;
      run += tmp;
    }
  }
}

// ---------------------------------------------------------------------------
// Attention phase C: per-chunk output.
//   num[t] = Q[t] @ P  +  sum_{s<=t} (Q[t].K[s]) V[s]
//   den[t] = Q[t].pk   +  sum_{s<=t}  Q[t].K[s]
// Qt/At stored transposed (stride 65) for conflict-free column access;
// KVP (stride 68) holds K, then V, then P.
// ---------------------------------------------------------------------------
__global__ __launch_bounds__(256) void attn_out(const float* __restrict__ q,
                                                const float* __restrict__ k,
                                                const float* __restrict__ v,
                                                const float* __restrict__ S,
                                                const float* __restrict__ Ksum,
                                                float* __restrict__ y) {
  __shared__ float Qt[64][65];
  __shared__ float KVP[64][68];
  __shared__ float At[64][65];
  const int g = blockIdx.x;
  const int j = g & (NCHK - 1), bh = g >> 4;
  const int b = bh >> 4, h = bh & (Hh - 1);
  const int tid = threadIdx.x;
  const size_t rowbase = (((size_t)b * Tt + j * CHK) * Hh + h) * DHh;
  const size_t rstep = (size_t)Hh * DHh;
  for (int l = tid; l < 4096; l += 256) {
    const int s = l >> 6, d = l & 63;
    Qt[d][s] = q[rowbase + s * rstep + d];
    KVP[s][d] = k[rowbase + s * rstep + d];
  }
  __syncthreads();
  const int t = tid >> 2, sg = tid & 3;
  const float* pk = Ksum + (size_t)g * 64;
  // --- stage 1: masked scores + denominator ---
  float adot[16] = {};
  float qpk = 0.f;
  for (int c = 0; c < 16; ++c) {
    const float q0 = Qt[4 * c + 0][t], q1 = Qt[4 * c + 1][t];
    const float q2 = Qt[4 * c + 2][t], q3 = Qt[4 * c + 3][t];
    const float4 pk4 = *(const float4*)&pk[4 * c];
    qpk = fmaf(q0, pk4.x, fmaf(q1, pk4.y, fmaf(q2, pk4.z, fmaf(q3, pk4.w, qpk))));
#pragma unroll
    for (int i = 0; i < 16; ++i) {
      const float4 k4 = *(const float4*)&KVP[sg * 16 + i][4 * c];
      adot[i] = fmaf(q0, k4.x, fmaf(q1, k4.y, fmaf(q2, k4.z, fmaf(q3, k4.w, adot[i]))));
    }
  }
  float rs = 0.f;
#pragma unroll
  for (int i = 0; i < 16; ++i) {
    if (sg * 16 + i > t) adot[i] = 0.f;
    rs += adot[i];
  }
  rs += __shfl_xor(rs, 1);
  rs += __shfl_xor(rs, 2);
  const float den = qpk + rs + 1e-6f;
  __syncthreads();  // all K reads complete
#pragma unroll
  for (int i = 0; i < 16; ++i) At[sg * 16 + i][t] = adot[i];
  for (int l = tid; l < 4096; l += 256) {  // overwrite K with V
    const int s = l >> 6, d = l & 63;
    KVP[s][d] = v[rowbase + s * rstep + d];
  }
  __syncthreads();
  // --- stage 2a: masked-score @ V ---
  const int e0 = sg * 16;
  float4 num[4] = {};
  for (int s = 0; s <= t; ++s) {
    const float av = At[s][t];
#pragma unroll
    for (int i = 0; i < 4; ++i) {
      const float4 v4 = *(const float4*)&KVP[s][e0 + 4 * i];
      num[i].x = fmaf(av, v4.x, num[i].x);
      num[i].y = fmaf(av, v4.y, num[i].y);
      num[i].z = fmaf(av, v4.z, num[i].z);
      num[i].w = fmaf(av, v4.w, num[i].w);
    }
  }
  __syncthreads();  // all V reads complete
  const float* Pg = S + (size_t)g * 4096;
  for (int l = tid; l < 4096; l += 256) KVP[l >> 6][l & 63] = Pg[l];
  __syncthreads();
  // --- stage 2b: Q @ P ---
  for (int d = 0; d < 64; ++d) {
    const float qd = Qt[d][t];
#pragma unroll
    for (int i = 0; i < 4; ++i) {
      const float4 p4 = *(const float4*)&KVP[d][e0 + 4 * i];
      num[i].x = fmaf(qd, p4.x, num[i].x);
      num[i].y = fmaf(qd, p4.y, num[i].y);
      num[i].z = fmaf(qd, p4.z, num[i].z);
      num[i].w = fmaf(qd, p4.w, num[i].w);
    }
  }
  const float inv = 1.f / den;
  float* yg = y + rowbase + t * rstep + e0;
#pragma unroll
  for (int i = 0; i < 4; ++i) {
    float4 o;
    o.x = num[i].x * inv;
    o.y = num[i].y * inv;
    o.z = num[i].z * inv;
    o.w = num[i].w * inv;
    *(float4*)&yg[4 * i] = o;
  }
}

// ---------------------------------------------------------------------------
// Per-head layernorm over DH=64, output bf16 [B,T,D].
// ---------------------------------------------------------------------------
__global__ __launch_bounds__(256) void ln_head(const float* __restrict__ y,
                                               const float* __restrict__ w,
                                               const float* __restrict__ bsh,
                                               __hip_bfloat16* __restrict__ out) {
  const int tid = threadIdx.x;
  const int e = tid & 63;
  const int r = blockIdx.x * 4 + (tid >> 6);
  const int h = r & (Hh - 1);
  const float val = y[(size_t)r * DHh + e];
  float s = val;
#pragma unroll
  for (int o = 1; o < 64; o <<= 1) s += __shfl_xor(s, o);
  const float mean = s * (1.f / 64.f);
  const float dv = val - mean;
  float s2 = dv * dv;
#pragma unroll
  for (int o = 1; o < 64; o <<= 1) s2 += __shfl_xor(s2, o);
  const float var = s2 * (1.f / 64.f);
  const float res = dv * rsqrtf(var + 1e-5f) * w[h * DHh + e] + bsh[h * DHh + e];
  out[(size_t)r * DHh + e] = __float2bfloat16(res);
}

// ---------------------------------------------------------------------------
// Residual + final layernorm over D=1024.
// ---------------------------------------------------------------------------
__global__ __launch_bounds__(256) void final_ln(const float* __restrict__ x,
                                                const float* __restrict__ f2,
                                                const float* __restrict__ w,
                                                const float* __restrict__ bb,
                                                float* __restrict__ out) {
  __shared__ float r1[4], r2[4];
  const int row = blockIdx.x;
  const int tid = threadIdx.x;
  const size_t off = (size_t)row * Dd + tid * 4;
  const float4 xa = *(const float4*)&x[off];
  const float4 fa = *(const float4*)&f2[off];
  float z[4] = {xa.x + fa.x, xa.y + fa.y, xa.z + fa.z, xa.w + fa.w};
  float s1 = z[0] + z[1] + z[2] + z[3];
  float s2 = z[0] * z[0] + z[1] * z[1] + z[2] * z[2] + z[3] * z[3];
#pragma unroll
  for (int o = 1; o < 64; o <<= 1) {
    s1 += __shfl_xor(s1, o);
    s2 += __shfl_xor(s2, o);
  }
  const int wid = tid >> 6;
  if ((tid & 63) == 0) {
    r1[wid] = s1;
    r2[wid] = s2;
  }
  __syncthreads();
  const float t1 = r1[0] + r1[1] + r1[2] + r1[3];
  const float t2 = r2[0] + r2[1] + r2[2] + r2[3];
  const float mu = t1 * (1.f / Dd);
  const float var = t2 * (1.f / Dd) - mu * mu;
  const float rsv = rsqrtf(var + 1e-5f);
  float4 o4;
  float* op = &o4.x;
#pragma unroll
  for (int jj = 0; jj < 4; ++jj) op[jj] = (z[jj] - mu) * rsv * w[tid * 4 + jj] + bb[tid * 4 + jj];
  *(float4*)&out[off] = o4;
}

// ---------------------------------------------------------------------------
extern "C" void kernel_launch(void* const* d_in, const int* in_sizes, int n_in,
                              void* d_out, int out_size, void* d_ws, size_t ws_size,
                              hipStream_t stream) {
  const float* x = (const float*)d_in[0];
  const float* W_amp = (const float*)d_in[1];
  const float* b_amp = (const float*)d_in[2];
  const float* W_phi = (const float*)d_in[3];
  const float* b_phi = (const float*)d_in[4];
  const float* omega = (const float*)d_in[5];
  const float* ret_logit = (const float*)d_in[6];
  const float* theta = (const float*)d_in[7];
  const float* W_feat = (const float*)d_in[8];
  const float* b_feat = (const float*)d_in[9];
  const float* Wq = (const float*)d_in[10];
  const float* Wk = (const float*)d_in[11];
  const float* Wv = (const float*)d_in[12];
  const float* lnh_w = (const float*)d_in[13];
  const float* lnh_b = (const float*)d_in[14];
  const float* W1 = (const float*)d_in[15];
  const float* b1 = (const float*)d_in[16];
  const float* W2 = (const float*)d_in[17];
  const float* b2 = (const float*)d_in[18];
  const float* ln_w = (const float*)d_in[19];
  const float* ln_b = (const float*)d_in[20];

  // ---- workspace bump allocator (256B aligned) ----
  char* p = (char*)d_ws;
  auto alloc = [&](size_t bytes) {
    char* r = p;
    p += (bytes + 255) & ~(size_t)255;
    return r;
  };
  __hip_bfloat16* xb = (__hip_bfloat16*)alloc((size_t)Mm * Dd * 2);  // later: featb
  float* ur = (float*)alloc((size_t)Mm * NFf * 4);
  float* ui = (float*)alloc((size_t)Mm * NFf * 4);
  __hip_bfloat16* WTamp = (__hip_bfloat16*)alloc((size_t)NFf * Dd * 2);
  __hip_bfloat16* WTphi = (__hip_bfloat16*)alloc((size_t)NFf * Dd * 2);
  __hip_bfloat16* WTfeat = (__hip_bfloat16*)alloc((size_t)Dd * 3 * NFf * 2);
  __hip_bfloat16* WTq = (__hip_bfloat16*)alloc((size_t)Dd * Dd * 2);
  __hip_bfloat16* WTk = (__hip_bfloat16*)alloc((size_t)Dd * Dd * 2);
  __hip_bfloat16* WTv = (__hip_bfloat16*)alloc((size_t)Dd * Dd * 2);
  __hip_bfloat16* WT1 = (__hip_bfloat16*)alloc((size_t)Rr * Dd * 2);
  __hip_bfloat16* WT2 = (__hip_bfloat16*)alloc((size_t)Dd * Rr * 2);
  __hip_bfloat16* hb = (__hip_bfloat16*)alloc((size_t)Mm * Dd * 2);
  float* q = (float*)alloc((size_t)Mm * Dd * 4);  // later: yhb (bf16)
  float* k = (float*)alloc((size_t)Mm * Dd * 4);  // later: f1b (spans k+v)
  float* v = (float*)alloc((size_t)Mm * Dd * 4);
  float* y = (float*)alloc((size_t)Mm * Dd * 4);  // later: f2
  float* S = (float*)alloc((size_t)Bb * Hh * NCHK * 4096 * 4);
  float* Ksum = (float*)alloc((size_t)Bb * Hh * NCHK * 64 * 4);
  __hip_bfloat16* featb = xb;
  __hip_bfloat16* yhb = (__hip_bfloat16*)q;
  __hip_bfloat16* f1b = (__hip_bfloat16*)k;
  float* f2 = y;
  float* out = (float*)d_out;

  const dim3 blk(256);

  // 0: casts
  cast_x<<<dim3(Mm * Dd / 1024), blk, 0, stream>>>(x, xb);
  TCDesc tc;
  tc.src[0] = W_amp; tc.dst[0] = WTamp;
  tc.src[1] = W_phi; tc.dst[1] = WTphi;
  tc.src[2] = W_feat; tc.dst[2] = WTfeat;
  tc.src[3] = Wq; tc.dst[3] = WTq;
  tc.src[4] = Wk; tc.dst[4] = WTk;
  tc.src[5] = Wv; tc.dst[5] = WTv;
  tc.src[6] = W1; tc.dst[6] = WT1;
  tc.src[7] = W2; tc.dst[7] = WT2;
  transpose_cast_all<<<dim3(12544), blk, 0, stream>>>(tc);

  // 1-2: resonator input projections (fp32 out into ur/ui buffers pre-polar)
  gemm_mfma<EPI_SOFTPLUS, 0><<<dim3(NFf / 128, Mm / 128), blk, 0, stream>>>(
      (const short*)xb, (const short*)WTamp, b_amp, ur, nullptr, Mm, NFf, Dd);
  gemm_mfma<EPI_TANHPI, 0><<<dim3(NFf / 128, Mm / 128), blk, 0, stream>>>(
      (const short*)xb, (const short*)WTphi, b_phi, ui, nullptr, Mm, NFf, Dd);
  polar_kernel<<<dim3(Mm * NFf / 256), blk, 0, stream>>>(ur, ui);

  // 3: resonator scan -> feat (bf16)
  resonator_scan<<<dim3(Bb), blk, 0, stream>>>(ur, ui, omega, ret_logit, theta, featb);

  // 4: feat projection -> h (bf16)
  gemm_mfma<EPI_RELU, 1><<<dim3(Dd / 128, Mm / 128), blk, 0, stream>>>(
      (const short*)featb, (const short*)WTfeat, b_feat, nullptr, hb, Mm, Dd, 3 * NFf);

  // 5-7: q,k,v projections (fp32 out)
  gemm_mfma<EPI_RELU, 0><<<dim3(Dd / 128, Mm / 128), blk, 0, stream>>>(
      (const short*)hb, (const short*)WTq, nullptr, q, nullptr, Mm, Dd, Dd);
  gemm_mfma<EPI_RELU, 0><<<dim3(Dd / 128, Mm / 128), blk, 0, stream>>>(
      (const short*)hb, (const short*)WTk, nullptr, k, nullptr, Mm, Dd, Dd);
  gemm_mfma<EPI_NONE, 0><<<dim3(Dd / 128, Mm / 128), blk, 0, stream>>>(
      (const short*)hb, (const short*)WTv, nullptr, v, nullptr, Mm, Dd, Dd);

  // 8: chunked causal linear attention
  attn_chunk_kv<<<dim3(Bb * Hh * NCHK), blk, 0, stream>>>(k, v, S, Ksum);
  attn_prefix<<<dim3(Bb * Hh), blk, 0, stream>>>(S, Ksum);
  attn_out<<<dim3(Bb * Hh * NCHK), blk, 0, stream>>>(q, k, v, S, Ksum, y);

  // 9: per-head layernorm -> bf16
  ln_head<<<dim3(Bb * Tt * Hh / 4), blk, 0, stream>>>(y, lnh_w, lnh_b, yhb);

  // 10-11: low-rank FFN
  gemm_mfma<EPI_RELU, 1><<<dim3(Rr / 128, Mm / 128), blk, 0, stream>>>(
      (const short*)yhb, (const short*)WT1, b1, nullptr, f1b, Mm, Rr, Dd);
  gemm_mfma<EPI_RELU, 0><<<dim3(Dd / 128, Mm / 128), blk, 0, stream>>>(
      (const short*)f1b, (const short*)WT2, b2, f2, nullptr, Mm, Dd, Rr);

  // 12: residual + final layernorm
  final_ln<<<dim3(Mm), blk, 0, stream>>>(x, f2, ln_w, ln_b, out);
}

// Round 3
// 521.883 us; speedup vs baseline: 3.6516x; 1.2259x over previous
//
#include <hip/hip_runtime.h>
#include <hip/hip_bf16.h>
#include <math.h>

#ifndef M_PI_F
#define M_PI_F 3.14159265358979323846f
#endif

static constexpr int Bb = 2, Tt = 1024, Dd = 1024, Hh = 16, DHh = 64, NFf = 256, Rr = 4096;
static constexpr int Mm = Bb * Tt;
static constexpr int CHK = 64, NCHK = Tt / CHK;  // attention chunking

enum Epi { EPI_NONE = 0, EPI_RELU, EPI_SOFTPLUS, EPI_TANHPI };

typedef __attribute__((ext_vector_type(8))) short bf16x8;
typedef __attribute__((ext_vector_type(4))) float f32x4;

// ---------------------------------------------------------------------------
// async global->LDS, 16B per lane. LDS dest is wave-uniform base; HW adds
// lane*16. Global address is per-lane.
// ---------------------------------------------------------------------------
__device__ inline void gload16(const short* g, short* l) {
  __builtin_amdgcn_global_load_lds(
      (const __attribute__((address_space(1))) unsigned int*)g,
      (__attribute__((address_space(3))) unsigned int*)l, 16, 0, 0);
}

// ---------------------------------------------------------------------------
// bf16 MFMA GEMM: C[M,N] = epi(A[M,K] @ BT[N,K]^T + bias)
// 128x128 tile, BK=64, 4 waves (2x2), each wave 64x64 via 4x4 frags of
// 16x16x32 MFMA. Single-buffer 2-barrier K-loop (m97 structure).
// ---------------------------------------------------------------------------
template <int EPI, int OUTBF>
__global__ __launch_bounds__(256) void gemm_mfma(const short* __restrict__ A,
                                                 const short* __restrict__ BT,
                                                 const float* __restrict__ bias,
                                                 float* __restrict__ Cf,
                                                 __hip_bfloat16* __restrict__ Cb,
                                                 int M, int N, int K) {
  __shared__ short lA[128 * 64];
  __shared__ short lB[128 * 64];
  const int tid = threadIdx.x;
  const int wid = tid >> 6, lane = tid & 63;
  const int m0 = blockIdx.y * 128, n0 = blockIdx.x * 128;
  const int wm = (wid >> 1) * 64, wn = (wid & 1) * 64;
  const int srow = lane >> 3;          // row within 8-row stage slab
  const int skk = (lane & 7) * 8;      // k offset (elements)

  f32x4 acc[4][4] = {};

  for (int k0 = 0; k0 < K; k0 += 64) {
#pragma unroll
    for (int si = 0; si < 4; ++si) {
      const int s = wid + si * 4;  // stage instruction index 0..15
      gload16(A + (size_t)(m0 + s * 8 + srow) * K + k0 + skk, &lA[s * 512]);
      gload16(BT + (size_t)(n0 + s * 8 + srow) * K + k0 + skk, &lB[s * 512]);
    }
    __syncthreads();  // drains vmcnt -> LDS tiles ready
#pragma unroll
    for (int kk = 0; kk < 2; ++kk) {
      const int krd = kk * 32 + (lane >> 4) * 8;
      const int rsel = lane & 15;
      bf16x8 af[4], bfr[4];
#pragma unroll
      for (int i = 0; i < 4; ++i) {
        af[i] = *(const bf16x8*)&lA[(wm + i * 16 + rsel) * 64 + krd];
        bfr[i] = *(const bf16x8*)&lB[(wn + i * 16 + rsel) * 64 + krd];
      }
#pragma unroll
      for (int i = 0; i < 4; ++i)
#pragma unroll
        for (int j = 0; j < 4; ++j)
          acc[i][j] = __builtin_amdgcn_mfma_f32_16x16x32_bf16(af[i], bfr[j], acc[i][j], 0, 0, 0);
    }
    __syncthreads();  // compute done before restage
  }

  const int crow = (lane >> 4) * 4;
  const int ccol = lane & 15;
#pragma unroll
  for (int j = 0; j < 4; ++j) {
    const int col = n0 + wn + j * 16 + ccol;
    const float bv = bias ? bias[col] : 0.f;
#pragma unroll
    for (int i = 0; i < 4; ++i) {
#pragma unroll
      for (int r = 0; r < 4; ++r) {
        float v = acc[i][j][r] + bv;
        if (EPI == EPI_RELU) {
          v = fmaxf(v, 0.f);
        } else if (EPI == EPI_SOFTPLUS) {
          v = (v > 0.f) ? (v + log1pf(expf(-v))) : log1pf(expf(v));
        } else if (EPI == EPI_TANHPI) {
          v = M_PI_F * tanhf(v);
        }
        const size_t off = (size_t)(m0 + wm + i * 16 + crow + r) * N + col;
        if (OUTBF)
          Cb[off] = __float2bfloat16(v);
        else
          Cf[off] = v;
      }
    }
  }
}

// ---------------------------------------------------------------------------
// Fused transpose-cast of all 8 weight matrices: W[K,N] f32 -> WT[N,K] bf16.
// ---------------------------------------------------------------------------
struct TCDesc {
  const float* src[8];
  __hip_bfloat16* dst[8];
};

__global__ __launch_bounds__(256) void transpose_cast_all(TCDesc d) {
  constexpr int KS[8] = {1024, 1024, 768, 1024, 1024, 1024, 1024, 4096};
  constexpr int NS[8] = {256, 256, 1024, 1024, 1024, 1024, 4096, 1024};
  constexpr int CUM[9] = {0, 256, 512, 1280, 2304, 3328, 4352, 8448, 12544};
  __shared__ float tile[32][33];
  const int bid = blockIdx.x;
  int w = 0;
#pragma unroll
  for (int i = 0; i < 8; ++i)
    if (bid >= CUM[i + 1]) w = i + 1;
  const int tlocal = bid - CUM[w];
  const int K = KS[w], N = NS[w];
  const int tilesN = N / 32;
  const int bk = (tlocal / tilesN) * 32, bn = (tlocal % tilesN) * 32;
  const float* W = d.src[w];
  __hip_bfloat16* WT = d.dst[w];
  const int tx = threadIdx.x & 31, ty = threadIdx.x >> 5;  // 32x8
#pragma unroll
  for (int r = 0; r < 32; r += 8) tile[ty + r][tx] = W[(size_t)(bk + ty + r) * N + bn + tx];
  __syncthreads();
#pragma unroll
  for (int r = 0; r < 32; r += 8)
    WT[(size_t)(bn + ty + r) * K + bk + tx] = __float2bfloat16(tile[tx][ty + r]);
}

// ---------------------------------------------------------------------------
// x: f32 -> bf16 cast (row-major, layout preserved)
// ---------------------------------------------------------------------------
__global__ __launch_bounds__(256) void cast_x(const float* __restrict__ x,
                                              __hip_bfloat16* __restrict__ xb) {
  const int i = (blockIdx.x * 256 + threadIdx.x) * 4;
  const float4 v = *(const float4*)&x[i];
  xb[i + 0] = __float2bfloat16(v.x);
  xb[i + 1] = __float2bfloat16(v.y);
  xb[i + 2] = __float2bfloat16(v.z);
  xb[i + 3] = __float2bfloat16(v.w);
}

// ---------------------------------------------------------------------------
// polar -> cartesian in place: (amp, phi) -> (amp*cos(phi), amp*sin(phi))
// ---------------------------------------------------------------------------
__global__ __launch_bounds__(256) void polar_kernel(float* __restrict__ a,
                                                    float* __restrict__ p) {
  const int i = blockIdx.x * 256 + threadIdx.x;
  const float am = a[i], ph = p[i];
  float s, c;
  sincosf(ph, &s, &c);
  a[i] = am * c;
  p[i] = am * s;
}

// ---------------------------------------------------------------------------
// Sequential complex resonator recurrence; writes feat bf16 [B,T,3*NF].
// Register-double-buffered prefetch (depth P=16): group g+1's ur/ui loads
// are issued before group g's 16-step ALU chain (~800+ cy), hiding L2
// latency (~200 cy) entirely. All buffer indexing is compile-time static.
// ---------------------------------------------------------------------------
static constexpr int RES_P = 16;

#define RES_LOAD(buf_r, buf_i, tg)                              \
  if ((tg) < Tt) {                                              \
    _Pragma("unroll") for (int i = 0; i < RES_P; ++i) {         \
      buf_r[i] = ur[bbase + (size_t)((tg) + i) * NFf];          \
      buf_i[i] = ui[bbase + (size_t)((tg) + i) * NFf];          \
    }                                                           \
  }

#define RES_STEP(buf_r, buf_i, tg)                              \
  _Pragma("unroll") for (int i = 0; i < RES_P; ++i) {           \
    const float pr = fmaf(ar, Xr, fmaf(-ai, Xi, buf_r[i]));     \
    const float pim = fmaf(ar, Xi, fmaf(ai, Xr, buf_i[i]));     \
    const float mag = sqrtf(fmaf(pr, pr, pim * pim));           \
    const float g = 1.f / (1.f + __expf(th - mag));             \
    Xr = pr * g;                                                \
    Xi = pim * g;                                               \
    const size_t fb = ((size_t)b * Tt + (tg) + i) * (3 * NFf);  \
    featb[fb + f] = __float2bfloat16(Xr);                       \
    featb[fb + NFf + f] = __float2bfloat16(Xi);                 \
    featb[fb + 2 * NFf + f] = __float2bfloat16(mag * g);        \
  }

__global__ __launch_bounds__(256) void resonator_scan(const float* __restrict__ ur,
                                                      const float* __restrict__ ui,
                                                      const float* __restrict__ omega,
                                                      const float* __restrict__ ret_logit,
                                                      const float* __restrict__ theta,
                                                      __hip_bfloat16* __restrict__ featb) {
  const int f = threadIdx.x;
  const int b = blockIdx.x;
  const float dec = 1.f / (1.f + __expf(-ret_logit[f]));
  float so, co;
  sincosf(omega[f], &so, &co);
  const float ar = dec * co, ai = dec * so;
  const float th = theta[f];
  const size_t bbase = (size_t)b * Tt * NFf + f;
  float Xr = 0.f, Xi = 0.f;
  float Ar[RES_P], Ai[RES_P], Br[RES_P], Bi[RES_P];
  RES_LOAD(Ar, Ai, 0);
  for (int t0 = 0; t0 < Tt; t0 += 2 * RES_P) {
    RES_LOAD(Br, Bi, t0 + RES_P);
    RES_STEP(Ar, Ai, t0);
    RES_LOAD(Ar, Ai, t0 + 2 * RES_P);
    RES_STEP(Br, Bi, t0 + RES_P);
  }
}

// ---------------------------------------------------------------------------
// Attention phase A: per-chunk KV outer-product sums and k-sums.
// grid = B*H*NCHK; S[g][d][e] (64x64), Ksum[g][d].
// ---------------------------------------------------------------------------
__global__ __launch_bounds__(256) void attn_chunk_kv(const float* __restrict__ k,
                                                     const float* __restrict__ v,
                                                     float* __restrict__ S,
                                                     float* __restrict__ Ksum) {
  __shared__ float Ks[64][68], Vs[64][68];
  const int g = blockIdx.x;
  const int j = g & (NCHK - 1), bh = g >> 4;
  const int b = bh >> 4, h = bh & (Hh - 1);
  const int tid = threadIdx.x;
  const size_t rowbase = (((size_t)b * Tt + j * CHK) * Hh + h) * DHh;
  const size_t rstep = (size_t)Hh * DHh;
  for (int l = tid; l < 4096; l += 256) {
    const int s = l >> 6, d = l & 63;
    Ks[s][d] = k[rowbase + s * rstep + d];
    Vs[s][d] = v[rowbase + s * rstep + d];
  }
  __syncthreads();
  const int d0 = tid & 63, eb = tid >> 6, e0 = eb * 16;
  float4 acc4[4] = {};
  float ks = 0.f;
  for (int s = 0; s < 64; ++s) {
    const float kd = Ks[s][d0];
    ks += kd;
#pragma unroll
    for (int i = 0; i < 4; ++i) {
      const float4 v4 = *(const float4*)&Vs[s][e0 + 4 * i];
      acc4[i].x = fmaf(kd, v4.x, acc4[i].x);
      acc4[i].y = fmaf(kd, v4.y, acc4[i].y);
      acc4[i].z = fmaf(kd, v4.z, acc4[i].z);
      acc4[i].w = fmaf(kd, v4.w, acc4[i].w);
    }
  }
  float* Sg = S + (size_t)g * 4096 + (size_t)d0 * 64 + e0;
#pragma unroll
  for (int i = 0; i < 4; ++i) *(float4*)&Sg[4 * i] = acc4[i];
  if (eb == 0) Ksum[(size_t)g * 64 + d0] = ks;
}

// ---------------------------------------------------------------------------
// Attention phase B: in-place EXCLUSIVE prefix over the 16 chunks per (b,h).
// ---------------------------------------------------------------------------
__global__ __launch_bounds__(256) void attn_prefix(float* __restrict__ S,
                                                   float* __restrict__ Ksum) {
  const int bh = blockIdx.x;
  const int tid = threadIdx.x;
  for (int r = 0; r < 16; ++r) {
    const int de = r * 256 + tid;
    float run = 0.f;
    size_t p = (size_t)bh * (NCHK * 4096) + de;
    for (int j = 0; j < NCHK; ++j, p += 4096) {
      const float tmp = S[p];
      S[p] = run;
      run += tmp;
    }
  }
  if (tid < 64) {
    float run = 0.f;
    size_t p = (size_t)bh * (NCHK * 64) + tid;
    for (int j = 0; j < NCHK; ++j, p += 64) {
      const float tmp = Ksum[p];
      Ksum[p] = run;
      run += tmp;
    }
  }
}

// ---------------------------------------------------------------------------
// Attention phase C: per-chunk output.
//   num[t] = Q[t] @ P  +  sum_{s<=t} (Q[t].K[s]) V[s]
//   den[t] = Q[t].pk   +  sum_{s<=t}  Q[t].K[s]
// Qt/At stored transposed (stride 65) for conflict-free column access;
// KVP (stride 68) holds K, then V, then P.
// ---------------------------------------------------------------------------
__global__ __launch_bounds__(256) void attn_out(const float* __restrict__ q,
                                                const float* __restrict__ k,
                                                const float* __restrict__ v,
                                                const float* __restrict__ S,
                                                const float* __restrict__ Ksum,
                                                float* __restrict__ y) {
  __shared__ float Qt[64][65];
  __shared__ float KVP[64][68];
  __shared__ float At[64][65];
  const int g = blockIdx.x;
  const int j = g & (NCHK - 1), bh = g >> 4;
  const int b = bh >> 4, h = bh & (Hh - 1);
  const int tid = threadIdx.x;
  const size_t rowbase = (((size_t)b * Tt + j * CHK) * Hh + h) * DHh;
  const size_t rstep = (size_t)Hh * DHh;
  for (int l = tid; l < 4096; l += 256) {
    const int s = l >> 6, d = l & 63;
    Qt[d][s] = q[rowbase + s * rstep + d];
    KVP[s][d] = k[rowbase + s * rstep + d];
  }
  __syncthreads();
  const int t = tid >> 2, sg = tid & 3;
  const float* pk = Ksum + (size_t)g * 64;
  // --- stage 1: masked scores + denominator ---
  float adot[16] = {};
  float qpk = 0.f;
  for (int c = 0; c < 16; ++c) {
    const float q0 = Qt[4 * c + 0][t], q1 = Qt[4 * c + 1][t];
    const float q2 = Qt[4 * c + 2][t], q3 = Qt[4 * c + 3][t];
    const float4 pk4 = *(const float4*)&pk[4 * c];
    qpk = fmaf(q0, pk4.x, fmaf(q1, pk4.y, fmaf(q2, pk4.z, fmaf(q3, pk4.w, qpk))));
#pragma unroll
    for (int i = 0; i < 16; ++i) {
      const float4 k4 = *(const float4*)&KVP[sg * 16 + i][4 * c];
      adot[i] = fmaf(q0, k4.x, fmaf(q1, k4.y, fmaf(q2, k4.z, fmaf(q3, k4.w, adot[i]))));
    }
  }
  float rs = 0.f;
#pragma unroll
  for (int i = 0; i < 16; ++i) {
    if (sg * 16 + i > t) adot[i] = 0.f;
    rs += adot[i];
  }
  rs += __shfl_xor(rs, 1);
  rs += __shfl_xor(rs, 2);
  const float den = qpk + rs + 1e-6f;
  __syncthreads();  // all K reads complete
#pragma unroll
  for (int i = 0; i < 16; ++i) At[sg * 16 + i][t] = adot[i];
  for (int l = tid; l < 4096; l += 256) {  // overwrite K with V
    const int s = l >> 6, d = l & 63;
    KVP[s][d] = v[rowbase + s * rstep + d];
  }
  __syncthreads();
  // --- stage 2a: masked-score @ V ---
  const int e0 = sg * 16;
  float4 num[4] = {};
  for (int s = 0; s <= t; ++s) {
    const float av = At[s][t];
#pragma unroll
    for (int i = 0; i < 4; ++i) {
      const float4 v4 = *(const float4*)&KVP[s][e0 + 4 * i];
      num[i].x = fmaf(av, v4.x, num[i].x);
      num[i].y = fmaf(av, v4.y, num[i].y);
      num[i].z = fmaf(av, v4.z, num[i].z);
      num[i].w = fmaf(av, v4.w, num[i].w);
    }
  }
  __syncthreads();  // all V reads complete
  const float* Pg = S + (size_t)g * 4096;
  for (int l = tid; l < 4096; l += 256) KVP[l >> 6][l & 63] = Pg[l];
  __syncthreads();
  // --- stage 2b: Q @ P ---
  for (int d = 0; d < 64; ++d) {
    const float qd = Qt[d][t];
#pragma unroll
    for (int i = 0; i < 4; ++i) {
      const float4 p4 = *(const float4*)&KVP[d][e0 + 4 * i];
      num[i].x = fmaf(qd, p4.x, num[i].x);
      num[i].y = fmaf(qd, p4.y, num[i].y);
      num[i].z = fmaf(qd, p4.z, num[i].z);
      num[i].w = fmaf(qd, p4.w, num[i].w);
    }
  }
  const float inv = 1.f / den;
  float* yg = y + rowbase + t * rstep + e0;
#pragma unroll
  for (int i = 0; i < 4; ++i) {
    float4 o;
    o.x = num[i].x * inv;
    o.y = num[i].y * inv;
    o.z = num[i].z * inv;
    o.w = num[i].w * inv;
    *(float4*)&yg[4 * i] = o;
  }
}

// ---------------------------------------------------------------------------
// Per-head layernorm over DH=64, output bf16 [B,T,D].
// ---------------------------------------------------------------------------
__global__ __launch_bounds__(256) void ln_head(const float* __restrict__ y,
                                               const float* __restrict__ w,
                                               const float* __restrict__ bsh,
                                               __hip_bfloat16* __restrict__ out) {
  const int tid = threadIdx.x;
  const int e = tid & 63;
  const int r = blockIdx.x * 4 + (tid >> 6);
  const int h = r & (Hh - 1);
  const float val = y[(size_t)r * DHh + e];
  float s = val;
#pragma unroll
  for (int o = 1; o < 64; o <<= 1) s += __shfl_xor(s, o);
  const float mean = s * (1.f / 64.f);
  const float dv = val - mean;
  float s2 = dv * dv;
#pragma unroll
  for (int o = 1; o < 64; o <<= 1) s2 += __shfl_xor(s2, o);
  const float var = s2 * (1.f / 64.f);
  const float res = dv * rsqrtf(var + 1e-5f) * w[h * DHh + e] + bsh[h * DHh + e];
  out[(size_t)r * DHh + e] = __float2bfloat16(res);
}

// ---------------------------------------------------------------------------
// Residual + final layernorm over D=1024.
// ---------------------------------------------------------------------------
__global__ __launch_bounds__(256) void final_ln(const float* __restrict__ x,
                                                const float* __restrict__ f2,
                                                const float* __restrict__ w,
                                                const float* __restrict__ bb,
                                                float* __restrict__ out) {
  __shared__ float r1[4], r2[4];
  const int row = blockIdx.x;
  const int tid = threadIdx.x;
  const size_t off = (size_t)row * Dd + tid * 4;
  const float4 xa = *(const float4*)&x[off];
  const float4 fa = *(const float4*)&f2[off];
  float z[4] = {xa.x + fa.x, xa.y + fa.y, xa.z + fa.z, xa.w + fa.w};
  float s1 = z[0] + z[1] + z[2] + z[3];
  float s2 = z[0] * z[0] + z[1] * z[1] + z[2] * z[2] + z[3] * z[3];
#pragma unroll
  for (int o = 1; o < 64; o <<= 1) {
    s1 += __shfl_xor(s1, o);
    s2 += __shfl_xor(s2, o);
  }
  const int wid = tid >> 6;
  if ((tid & 63) == 0) {
    r1[wid] = s1;
    r2[wid] = s2;
  }
  __syncthreads();
  const float t1 = r1[0] + r1[1] + r1[2] + r1[3];
  const float t2 = r2[0] + r2[1] + r2[2] + r2[3];
  const float mu = t1 * (1.f / Dd);
  const float var = t2 * (1.f / Dd) - mu * mu;
  const float rsv = rsqrtf(var + 1e-5f);
  float4 o4;
  float* op = &o4.x;
#pragma unroll
  for (int jj = 0; jj < 4; ++jj) op[jj] = (z[jj] - mu) * rsv * w[tid * 4 + jj] + bb[tid * 4 + jj];
  *(float4*)&out[off] = o4;
}

// ---------------------------------------------------------------------------
extern "C" void kernel_launch(void* const* d_in, const int* in_sizes, int n_in,
                              void* d_out, int out_size, void* d_ws, size_t ws_size,
                              hipStream_t stream) {
  const float* x = (const float*)d_in[0];
  const float* W_amp = (const float*)d_in[1];
  const float* b_amp = (const float*)d_in[2];
  const float* W_phi = (const float*)d_in[3];
  const float* b_phi = (const float*)d_in[4];
  const float* omega = (const float*)d_in[5];
  const float* ret_logit = (const float*)d_in[6];
  const float* theta = (const float*)d_in[7];
  const float* W_feat = (const float*)d_in[8];
  const float* b_feat = (const float*)d_in[9];
  const float* Wq = (const float*)d_in[10];
  const float* Wk = (const float*)d_in[11];
  const float* Wv = (const float*)d_in[12];
  const float* lnh_w = (const float*)d_in[13];
  const float* lnh_b = (const float*)d_in[14];
  const float* W1 = (const float*)d_in[15];
  const float* b1 = (const float*)d_in[16];
  const float* W2 = (const float*)d_in[17];
  const float* b2 = (const float*)d_in[18];
  const float* ln_w = (const float*)d_in[19];
  const float* ln_b = (const float*)d_in[20];

  // ---- workspace bump allocator (256B aligned) ----
  char* p = (char*)d_ws;
  auto alloc = [&](size_t bytes) {
    char* r = p;
    p += (bytes + 255) & ~(size_t)255;
    return r;
  };
  __hip_bfloat16* xb = (__hip_bfloat16*)alloc((size_t)Mm * Dd * 2);  // later: featb
  float* ur = (float*)alloc((size_t)Mm * NFf * 4);
  float* ui = (float*)alloc((size_t)Mm * NFf * 4);
  __hip_bfloat16* WTamp = (__hip_bfloat16*)alloc((size_t)NFf * Dd * 2);
  __hip_bfloat16* WTphi = (__hip_bfloat16*)alloc((size_t)NFf * Dd * 2);
  __hip_bfloat16* WTfeat = (__hip_bfloat16*)alloc((size_t)Dd * 3 * NFf * 2);
  __hip_bfloat16* WTq = (__hip_bfloat16*)alloc((size_t)Dd * Dd * 2);
  __hip_bfloat16* WTk = (__hip_bfloat16*)alloc((size_t)Dd * Dd * 2);
  __hip_bfloat16* WTv = (__hip_bfloat16*)alloc((size_t)Dd * Dd * 2);
  __hip_bfloat16* WT1 = (__hip_bfloat16*)alloc((size_t)Rr * Dd * 2);
  __hip_bfloat16* WT2 = (__hip_bfloat16*)alloc((size_t)Dd * Rr * 2);
  __hip_bfloat16* hb = (__hip_bfloat16*)alloc((size_t)Mm * Dd * 2);
  float* q = (float*)alloc((size_t)Mm * Dd * 4);  // later: yhb (bf16)
  float* k = (float*)alloc((size_t)Mm * Dd * 4);  // later: f1b (spans k+v)
  float* v = (float*)alloc((size_t)Mm * Dd * 4);
  float* y = (float*)alloc((size_t)Mm * Dd * 4);  // later: f2
  float* S = (float*)alloc((size_t)Bb * Hh * NCHK * 4096 * 4);
  float* Ksum = (float*)alloc((size_t)Bb * Hh * NCHK * 64 * 4);
  __hip_bfloat16* featb = xb;
  __hip_bfloat16* yhb = (__hip_bfloat16*)q;
  __hip_bfloat16* f1b = (__hip_bfloat16*)k;
  float* f2 = y;
  float* out = (float*)d_out;

  const dim3 blk(256);

  // 0: casts
  cast_x<<<dim3(Mm * Dd / 1024), blk, 0, stream>>>(x, xb);
  TCDesc tc;
  tc.src[0] = W_amp; tc.dst[0] = WTamp;
  tc.src[1] = W_phi; tc.dst[1] = WTphi;
  tc.src[2] = W_feat; tc.dst[2] = WTfeat;
  tc.src[3] = Wq; tc.dst[3] = WTq;
  tc.src[4] = Wk; tc.dst[4] = WTk;
  tc.src[5] = Wv; tc.dst[5] = WTv;
  tc.src[6] = W1; tc.dst[6] = WT1;
  tc.src[7] = W2; tc.dst[7] = WT2;
  transpose_cast_all<<<dim3(12544), blk, 0, stream>>>(tc);

  // 1-2: resonator input projections (fp32 out into ur/ui buffers pre-polar)
  gemm_mfma<EPI_SOFTPLUS, 0><<<dim3(NFf / 128, Mm / 128), blk, 0, stream>>>(
      (const short*)xb, (const short*)WTamp, b_amp, ur, nullptr, Mm, NFf, Dd);
  gemm_mfma<EPI_TANHPI, 0><<<dim3(NFf / 128, Mm / 128), blk, 0, stream>>>(
      (const short*)xb, (const short*)WTphi, b_phi, ui, nullptr, Mm, NFf, Dd);
  polar_kernel<<<dim3(Mm * NFf / 256), blk, 0, stream>>>(ur, ui);

  // 3: resonator scan -> feat (bf16)
  resonator_scan<<<dim3(Bb), blk, 0, stream>>>(ur, ui, omega, ret_logit, theta, featb);

  // 4: feat projection -> h (bf16)
  gemm_mfma<EPI_RELU, 1><<<dim3(Dd / 128, Mm / 128), blk, 0, stream>>>(
      (const short*)featb, (const short*)WTfeat, b_feat, nullptr, hb, Mm, Dd, 3 * NFf);

  // 5-7: q,k,v projections (fp32 out)
  gemm_mfma<EPI_RELU, 0><<<dim3(Dd / 128, Mm / 128), blk, 0, stream>>>(
      (const short*)hb, (const short*)WTq, nullptr, q, nullptr, Mm, Dd, Dd);
  gemm_mfma<EPI_RELU, 0><<<dim3(Dd / 128, Mm / 128), blk, 0, stream>>>(
      (const short*)hb, (const short*)WTk, nullptr, k, nullptr, Mm, Dd, Dd);
  gemm_mfma<EPI_NONE, 0><<<dim3(Dd / 128, Mm / 128), blk, 0, stream>>>(
      (const short*)hb, (const short*)WTv, nullptr, v, nullptr, Mm, Dd, Dd);

  // 8: chunked causal linear attention
  attn_chunk_kv<<<dim3(Bb * Hh * NCHK), blk, 0, stream>>>(k, v, S, Ksum);
  attn_prefix<<<dim3(Bb * Hh), blk, 0, stream>>>(S, Ksum);
  attn_out<<<dim3(Bb * Hh * NCHK), blk, 0, stream>>>(q, k, v, S, Ksum, y);

  // 9: per-head layernorm -> bf16
  ln_head<<<dim3(Bb * Tt * Hh / 4), blk, 0, stream>>>(y, lnh_w, lnh_b, yhb);

  // 10-11: low-rank FFN
  gemm_mfma<EPI_RELU, 1><<<dim3(Rr / 128, Mm / 128), blk, 0, stream>>>(
      (const short*)yhb, (const short*)WT1, b1, nullptr, f1b, Mm, Rr, Dd);
  gemm_mfma<EPI_RELU, 0><<<dim3(Dd / 128, Mm / 128), blk, 0, stream>>>(
      (const short*)f1b, (const short*)WT2, b2, f2, nullptr, Mm, Dd, Rr);

  // 12: residual + final layernorm
  final_ln<<<dim3(Mm), blk, 0, stream>>>(x, f2, ln_w, ln_b, out);
}

// Round 4
// 461.929 us; speedup vs baseline: 4.1255x; 1.1298x over previous
//
#include <hip/hip_runtime.h>
#include <hip/hip_bf16.h>
#include <math.h>

#ifndef M_PI_F
#define M_PI_F 3.14159265358979323846f
#endif

static constexpr int Bb = 2, Tt = 1024, Dd = 1024, Hh = 16, DHh = 64, NFf = 256, Rr = 4096;
static constexpr int Mm = Bb * Tt;
static constexpr int CHK = 64, NCHK = Tt / CHK;  // attention chunking

enum Epi { EPI_NONE = 0, EPI_RELU, EPI_SOFTPLUS, EPI_TANHPI };

typedef __attribute__((ext_vector_type(8))) short bf16x8;
typedef __attribute__((ext_vector_type(4))) float f32x4;

// ---------------------------------------------------------------------------
// async global->LDS, 16B per lane. LDS dest is wave-uniform base; HW adds
// lane*16. Global address is per-lane.
// ---------------------------------------------------------------------------
__device__ inline void gload16(const short* g, short* l) {
  __builtin_amdgcn_global_load_lds(
      (const __attribute__((address_space(1))) unsigned int*)g,
      (__attribute__((address_space(3))) unsigned int*)l, 16, 0, 0);
}

// ---------------------------------------------------------------------------
// bf16 MFMA GEMM: C[M,N] = epi(A[M,K] @ BT[N,K]^T + bias)
// 128x128 tile, BK=64, 4 waves (2x2), each wave 64x64 via 4x4 frags of
// 16x16x32 MFMA. Single-buffer 2-barrier K-loop (m97 structure).
// ---------------------------------------------------------------------------
template <int EPI, int OUTBF>
__global__ __launch_bounds__(256) void gemm_mfma(const short* __restrict__ A,
                                                 const short* __restrict__ BT,
                                                 const float* __restrict__ bias,
                                                 float* __restrict__ Cf,
                                                 __hip_bfloat16* __restrict__ Cb,
                                                 int M, int N, int K) {
  __shared__ short lA[128 * 64];
  __shared__ short lB[128 * 64];
  const int tid = threadIdx.x;
  const int wid = tid >> 6, lane = tid & 63;
  const int m0 = blockIdx.y * 128, n0 = blockIdx.x * 128;
  const int wm = (wid >> 1) * 64, wn = (wid & 1) * 64;
  const int srow = lane >> 3;          // row within 8-row stage slab
  const int skk = (lane & 7) * 8;      // k offset (elements)

  f32x4 acc[4][4] = {};

  for (int k0 = 0; k0 < K; k0 += 64) {
#pragma unroll
    for (int si = 0; si < 4; ++si) {
      const int s = wid + si * 4;  // stage instruction index 0..15
      gload16(A + (size_t)(m0 + s * 8 + srow) * K + k0 + skk, &lA[s * 512]);
      gload16(BT + (size_t)(n0 + s * 8 + srow) * K + k0 + skk, &lB[s * 512]);
    }
    __syncthreads();  // drains vmcnt -> LDS tiles ready
#pragma unroll
    for (int kk = 0; kk < 2; ++kk) {
      const int krd = kk * 32 + (lane >> 4) * 8;
      const int rsel = lane & 15;
      bf16x8 af[4], bfr[4];
#pragma unroll
      for (int i = 0; i < 4; ++i) {
        af[i] = *(const bf16x8*)&lA[(wm + i * 16 + rsel) * 64 + krd];
        bfr[i] = *(const bf16x8*)&lB[(wn + i * 16 + rsel) * 64 + krd];
      }
#pragma unroll
      for (int i = 0; i < 4; ++i)
#pragma unroll
        for (int j = 0; j < 4; ++j)
          acc[i][j] = __builtin_amdgcn_mfma_f32_16x16x32_bf16(af[i], bfr[j], acc[i][j], 0, 0, 0);
    }
    __syncthreads();  // compute done before restage
  }

  const int crow = (lane >> 4) * 4;
  const int ccol = lane & 15;
#pragma unroll
  for (int j = 0; j < 4; ++j) {
    const int col = n0 + wn + j * 16 + ccol;
    const float bv = bias ? bias[col] : 0.f;
#pragma unroll
    for (int i = 0; i < 4; ++i) {
#pragma unroll
      for (int r = 0; r < 4; ++r) {
        float v = acc[i][j][r] + bv;
        if (EPI == EPI_RELU) {
          v = fmaxf(v, 0.f);
        } else if (EPI == EPI_SOFTPLUS) {
          v = (v > 0.f) ? (v + log1pf(expf(-v))) : log1pf(expf(v));
        } else if (EPI == EPI_TANHPI) {
          v = M_PI_F * tanhf(v);
        }
        const size_t off = (size_t)(m0 + wm + i * 16 + crow + r) * N + col;
        if (OUTBF)
          Cb[off] = __float2bfloat16(v);
        else
          Cf[off] = v;
      }
    }
  }
}

// ---------------------------------------------------------------------------
// Fused transpose-cast of all 8 weight matrices: W[K,N] f32 -> WT[N,K] bf16.
// ---------------------------------------------------------------------------
struct TCDesc {
  const float* src[8];
  __hip_bfloat16* dst[8];
};

__global__ __launch_bounds__(256) void transpose_cast_all(TCDesc d) {
  constexpr int KS[8] = {1024, 1024, 768, 1024, 1024, 1024, 1024, 4096};
  constexpr int NS[8] = {256, 256, 1024, 1024, 1024, 1024, 4096, 1024};
  constexpr int CUM[9] = {0, 256, 512, 1280, 2304, 3328, 4352, 8448, 12544};
  __shared__ float tile[32][33];
  const int bid = blockIdx.x;
  int w = 0;
#pragma unroll
  for (int i = 0; i < 8; ++i)
    if (bid >= CUM[i + 1]) w = i + 1;
  const int tlocal = bid - CUM[w];
  const int K = KS[w], N = NS[w];
  const int tilesN = N / 32;
  const int bk = (tlocal / tilesN) * 32, bn = (tlocal % tilesN) * 32;
  const float* W = d.src[w];
  __hip_bfloat16* WT = d.dst[w];
  const int tx = threadIdx.x & 31, ty = threadIdx.x >> 5;  // 32x8
#pragma unroll
  for (int r = 0; r < 32; r += 8) tile[ty + r][tx] = W[(size_t)(bk + ty + r) * N + bn + tx];
  __syncthreads();
#pragma unroll
  for (int r = 0; r < 32; r += 8)
    WT[(size_t)(bn + ty + r) * K + bk + tx] = __float2bfloat16(tile[tx][ty + r]);
}

// ---------------------------------------------------------------------------
// x: f32 -> bf16 cast (row-major, layout preserved)
// ---------------------------------------------------------------------------
__global__ __launch_bounds__(256) void cast_x(const float* __restrict__ x,
                                              __hip_bfloat16* __restrict__ xb) {
  const int i = (blockIdx.x * 256 + threadIdx.x) * 4;
  const float4 v = *(const float4*)&x[i];
  xb[i + 0] = __float2bfloat16(v.x);
  xb[i + 1] = __float2bfloat16(v.y);
  xb[i + 2] = __float2bfloat16(v.z);
  xb[i + 3] = __float2bfloat16(v.w);
}

// ---------------------------------------------------------------------------
// polar -> cartesian in place: (amp, phi) -> (amp*cos(phi), amp*sin(phi))
// ---------------------------------------------------------------------------
__global__ __launch_bounds__(256) void polar_kernel(float* __restrict__ a,
                                                    float* __restrict__ p) {
  const int i = blockIdx.x * 256 + threadIdx.x;
  const float am = a[i], ph = p[i];
  float s, c;
  sincosf(ph, &s, &c);
  a[i] = am * c;
  p[i] = am * s;
}

// ---------------------------------------------------------------------------
// Sequential complex resonator recurrence; writes feat bf16 [B,T,3*NF].
// 8 blocks x 64 lanes: block owns (b, 64-freq slice) so the ~0.9 MB of
// traffic per block spreads over 8 CUs (was 2 -> per-CU VMEM-bound, r3).
// Register-double-buffered prefetch (P=16) hides L2/HBM latency under the
// 16-step ALU chain; raw v_sqrt/v_rcp shorten the serial chain.
// ---------------------------------------------------------------------------
static constexpr int RES_P = 16;

#define RES_LOAD(buf_r, buf_i, tg)                              \
  if ((tg) < Tt) {                                              \
    _Pragma("unroll") for (int i = 0; i < RES_P; ++i) {         \
      buf_r[i] = ur[bbase + (size_t)((tg) + i) * NFf];          \
      buf_i[i] = ui[bbase + (size_t)((tg) + i) * NFf];          \
    }                                                           \
  }

#define RES_STEP(buf_r, buf_i, tg)                              \
  _Pragma("unroll") for (int i = 0; i < RES_P; ++i) {           \
    const float pr = fmaf(ar, Xr, fmaf(-ai, Xi, buf_r[i]));     \
    const float pim = fmaf(ar, Xi, fmaf(ai, Xr, buf_i[i]));     \
    const float mag = __builtin_amdgcn_sqrtf(fmaf(pr, pr, pim * pim)); \
    const float g = __builtin_amdgcn_rcpf(1.f + __expf(th - mag));     \
    Xr = pr * g;                                                \
    Xi = pim * g;                                                \
    const size_t fb = ((size_t)b * Tt + (tg) + i) * (3 * NFf);  \
    featb[fb + f] = __float2bfloat16(Xr);                       \
    featb[fb + NFf + f] = __float2bfloat16(Xi);                 \
    featb[fb + 2 * NFf + f] = __float2bfloat16(mag * g);        \
  }

__global__ __launch_bounds__(64) void resonator_scan(const float* __restrict__ ur,
                                                     const float* __restrict__ ui,
                                                     const float* __restrict__ omega,
                                                     const float* __restrict__ ret_logit,
                                                     const float* __restrict__ theta,
                                                     __hip_bfloat16* __restrict__ featb) {
  const int b = blockIdx.x >> 2;                    // B = 2
  const int f = (blockIdx.x & 3) * 64 + threadIdx.x;  // 64-freq slice
  const float dec = 1.f / (1.f + __expf(-ret_logit[f]));
  float so, co;
  sincosf(omega[f], &so, &co);
  const float ar = dec * co, ai = dec * so;
  const float th = theta[f];
  const size_t bbase = (size_t)b * Tt * NFf + f;
  float Xr = 0.f, Xi = 0.f;
  float Ar[RES_P], Ai[RES_P], Br[RES_P], Bi[RES_P];
  RES_LOAD(Ar, Ai, 0);
  for (int t0 = 0; t0 < Tt; t0 += 2 * RES_P) {
    RES_LOAD(Br, Bi, t0 + RES_P);
    RES_STEP(Ar, Ai, t0);
    RES_LOAD(Ar, Ai, t0 + 2 * RES_P);
    RES_STEP(Br, Bi, t0 + RES_P);
  }
}

// ---------------------------------------------------------------------------
// Attention phase A: per-chunk KV outer-product sums and k-sums.
// grid = B*H*NCHK; S[g][d][e] (64x64), Ksum[g][d].
// ---------------------------------------------------------------------------
__global__ __launch_bounds__(256) void attn_chunk_kv(const float* __restrict__ k,
                                                     const float* __restrict__ v,
                                                     float* __restrict__ S,
                                                     float* __restrict__ Ksum) {
  __shared__ float Ks[64][68], Vs[64][68];
  const int g = blockIdx.x;
  const int j = g & (NCHK - 1), bh = g >> 4;
  const int b = bh >> 4, h = bh & (Hh - 1);
  const int tid = threadIdx.x;
  const size_t rowbase = (((size_t)b * Tt + j * CHK) * Hh + h) * DHh;
  const size_t rstep = (size_t)Hh * DHh;
  for (int l = tid; l < 4096; l += 256) {
    const int s = l >> 6, d = l & 63;
    Ks[s][d] = k[rowbase + s * rstep + d];
    Vs[s][d] = v[rowbase + s * rstep + d];
  }
  __syncthreads();
  const int d0 = tid & 63, eb = tid >> 6, e0 = eb * 16;
  float4 acc4[4] = {};
  float ks = 0.f;
  for (int s = 0; s < 64; ++s) {
    const float kd = Ks[s][d0];
    ks += kd;
#pragma unroll
    for (int i = 0; i < 4; ++i) {
      const float4 v4 = *(const float4*)&Vs[s][e0 + 4 * i];
      acc4[i].x = fmaf(kd, v4.x, acc4[i].x);
      acc4[i].y = fmaf(kd, v4.y, acc4[i].y);
      acc4[i].z = fmaf(kd, v4.z, acc4[i].z);
      acc4[i].w = fmaf(kd, v4.w, acc4[i].w);
    }
  }
  float* Sg = S + (size_t)g * 4096 + (size_t)d0 * 64 + e0;
#pragma unroll
  for (int i = 0; i < 4; ++i) *(float4*)&Sg[4 * i] = acc4[i];
  if (eb == 0) Ksum[(size_t)g * 64 + d0] = ks;
}

// ---------------------------------------------------------------------------
// Attention phase B: in-place EXCLUSIVE prefix over the 16 chunks per (b,h).
// ---------------------------------------------------------------------------
__global__ __launch_bounds__(256) void attn_prefix(float* __restrict__ S,
                                                   float* __restrict__ Ksum) {
  const int bh = blockIdx.x;
  const int tid = threadIdx.x;
  for (int r = 0; r < 16; ++r) {
    const int de = r * 256 + tid;
    float run = 0.f;
    size_t p = (size_t)bh * (NCHK * 4096) + de;
    for (int j = 0; j < NCHK; ++j, p += 4096) {
      const float tmp = S[p];
      S[p] = run;
      run += tmp;
    }
  }
  if (tid < 64) {
    float run = 0.f;
    size_t p = (size_t)bh * (NCHK * 64) + tid;
    for (int j = 0; j < NCHK; ++j, p += 64) {
      const float tmp = Ksum[p];
      Ksum[p] = run;
      run += tmp;
    }
  }
}

// ---------------------------------------------------------------------------
// Attention phase C: per-chunk output.
//   num[t] = Q[t] @ P  +  sum_{s<=t} (Q[t].K[s]) V[s]
//   den[t] = Q[t].pk   +  sum_{s<=t}  Q[t].K[s]
// Qt/At stored transposed (stride 65) for conflict-free column access;
// KVP (stride 68) holds K, then V, then P.
// ---------------------------------------------------------------------------
__global__ __launch_bounds__(256) void attn_out(const float* __restrict__ q,
                                                const float* __restrict__ k,
                                                const float* __restrict__ v,
                                                const float* __restrict__ S,
                                                const float* __restrict__ Ksum,
                                                float* __restrict__ y) {
  __shared__ float Qt[64][65];
  __shared__ float KVP[64][68];
  __shared__ float At[64][65];
  const int g = blockIdx.x;
  const int j = g & (NCHK - 1), bh = g >> 4;
  const int b = bh >> 4, h = bh & (Hh - 1);
  const int tid = threadIdx.x;
  const size_t rowbase = (((size_t)b * Tt + j * CHK) * Hh + h) * DHh;
  const size_t rstep = (size_t)Hh * DHh;
  for (int l = tid; l < 4096; l += 256) {
    const int s = l >> 6, d = l & 63;
    Qt[d][s] = q[rowbase + s * rstep + d];
    KVP[s][d] = k[rowbase + s * rstep + d];
  }
  __syncthreads();
  const int t = tid >> 2, sg = tid & 3;
  const float* pk = Ksum + (size_t)g * 64;
  // --- stage 1: masked scores + denominator ---
  float adot[16] = {};
  float qpk = 0.f;
  for (int c = 0; c < 16; ++c) {
    const float q0 = Qt[4 * c + 0][t], q1 = Qt[4 * c + 1][t];
    const float q2 = Qt[4 * c + 2][t], q3 = Qt[4 * c + 3][t];
    const float4 pk4 = *(const float4*)&pk[4 * c];
    qpk = fmaf(q0, pk4.x, fmaf(q1, pk4.y, fmaf(q2, pk4.z, fmaf(q3, pk4.w, qpk))));
#pragma unroll
    for (int i = 0; i < 16; ++i) {
      const float4 k4 = *(const float4*)&KVP[sg * 16 + i][4 * c];
      adot[i] = fmaf(q0, k4.x, fmaf(q1, k4.y, fmaf(q2, k4.z, fmaf(q3, k4.w, adot[i]))));
    }
  }
  float rs = 0.f;
#pragma unroll
  for (int i = 0; i < 16; ++i) {
    if (sg * 16 + i > t) adot[i] = 0.f;
    rs += adot[i];
  }
  rs += __shfl_xor(rs, 1);
  rs += __shfl_xor(rs, 2);
  const float den = qpk + rs + 1e-6f;
  __syncthreads();  // all K reads complete
#pragma unroll
  for (int i = 0; i < 16; ++i) At[sg * 16 + i][t] = adot[i];
  for (int l = tid; l < 4096; l += 256) {  // overwrite K with V
    const int s = l >> 6, d = l & 63;
    KVP[s][d] = v[rowbase + s * rstep + d];
  }
  __syncthreads();
  // --- stage 2a: masked-score @ V ---
  const int e0 = sg * 16;
  float4 num[4] = {};
  for (int s = 0; s <= t; ++s) {
    const float av = At[s][t];
#pragma unroll
    for (int i = 0; i < 4; ++i) {
      const float4 v4 = *(const float4*)&KVP[s][e0 + 4 * i];
      num[i].x = fmaf(av, v4.x, num[i].x);
      num[i].y = fmaf(av, v4.y, num[i].y);
      num[i].z = fmaf(av, v4.z, num[i].z);
      num[i].w = fmaf(av, v4.w, num[i].w);
    }
  }
  __syncthreads();  // all V reads complete
  const float* Pg = S + (size_t)g * 4096;
  for (int l = tid; l < 4096; l += 256) KVP[l >> 6][l & 63] = Pg[l];
  __syncthreads();
  // --- stage 2b: Q @ P ---
  for (int d = 0; d < 64; ++d) {
    const float qd = Qt[d][t];
#pragma unroll
    for (int i = 0; i < 4; ++i) {
      const float4 p4 = *(const float4*)&KVP[d][e0 + 4 * i];
      num[i].x = fmaf(qd, p4.x, num[i].x);
      num[i].y = fmaf(qd, p4.y, num[i].y);
      num[i].z = fmaf(qd, p4.z, num[i].z);
      num[i].w = fmaf(qd, p4.w, num[i].w);
    }
  }
  const float inv = 1.f / den;
  float* yg = y + rowbase + t * rstep + e0;
#pragma unroll
  for (int i = 0; i < 4; ++i) {
    float4 o;
    o.x = num[i].x * inv;
    o.y = num[i].y * inv;
    o.z = num[i].z * inv;
    o.w = num[i].w * inv;
    *(float4*)&yg[4 * i] = o;
  }
}

// ---------------------------------------------------------------------------
// Per-head layernorm over DH=64, output bf16 [B,T,D].
// ---------------------------------------------------------------------------
__global__ __launch_bounds__(256) void ln_head(const float* __restrict__ y,
                                               const float* __restrict__ w,
                                               const float* __restrict__ bsh,
                                               __hip_bfloat16* __restrict__ out) {
  const int tid = threadIdx.x;
  const int e = tid & 63;
  const int r = blockIdx.x * 4 + (tid >> 6);
  const int h = r & (Hh - 1);
  const float val = y[(size_t)r * DHh + e];
  float s = val;
#pragma unroll
  for (int o = 1; o < 64; o <<= 1) s += __shfl_xor(s, o);
  const float mean = s * (1.f / 64.f);
  const float dv = val - mean;
  float s2 = dv * dv;
#pragma unroll
  for (int o = 1; o < 64; o <<= 1) s2 += __shfl_xor(s2, o);
  const float var = s2 * (1.f / 64.f);
  const float res = dv * rsqrtf(var + 1e-5f) * w[h * DHh + e] + bsh[h * DHh + e];
  out[(size_t)r * DHh + e] = __float2bfloat16(res);
}

// ---------------------------------------------------------------------------
// Residual + final layernorm over D=1024.
// ---------------------------------------------------------------------------
__global__ __launch_bounds__(256) void final_ln(const float* __restrict__ x,
                                                const float* __restrict__ f2,
                                                const float* __restrict__ w,
                                                const float* __restrict__ bb,
                                                float* __restrict__ out) {
  __shared__ float r1[4], r2[4];
  const int row = blockIdx.x;
  const int tid = threadIdx.x;
  const size_t off = (size_t)row * Dd + tid * 4;
  const float4 xa = *(const float4*)&x[off];
  const float4 fa = *(const float4*)&f2[off];
  float z[4] = {xa.x + fa.x, xa.y + fa.y, xa.z + fa.z, xa.w + fa.w};
  float s1 = z[0] + z[1] + z[2] + z[3];
  float s2 = z[0] * z[0] + z[1] * z[1] + z[2] * z[2] + z[3] * z[3];
#pragma unroll
  for (int o = 1; o < 64; o <<= 1) {
    s1 += __shfl_xor(s1, o);
    s2 += __shfl_xor(s2, o);
  }
  const int wid = tid >> 6;
  if ((tid & 63) == 0) {
    r1[wid] = s1;
    r2[wid] = s2;
  }
  __syncthreads();
  const float t1 = r1[0] + r1[1] + r1[2] + r1[3];
  const float t2 = r2[0] + r2[1] + r2[2] + r2[3];
  const float mu = t1 * (1.f / Dd);
  const float var = t2 * (1.f / Dd) - mu * mu;
  const float rsv = rsqrtf(var + 1e-5f);
  float4 o4;
  float* op = &o4.x;
#pragma unroll
  for (int jj = 0; jj < 4; ++jj) op[jj] = (z[jj] - mu) * rsv * w[tid * 4 + jj] + bb[tid * 4 + jj];
  *(float4*)&out[off] = o4;
}

// ---------------------------------------------------------------------------
extern "C" void kernel_launch(void* const* d_in, const int* in_sizes, int n_in,
                              void* d_out, int out_size, void* d_ws, size_t ws_size,
                              hipStream_t stream) {
  const float* x = (const float*)d_in[0];
  const float* W_amp = (const float*)d_in[1];
  const float* b_amp = (const float*)d_in[2];
  const float* W_phi = (const float*)d_in[3];
  const float* b_phi = (const float*)d_in[4];
  const float* omega = (const float*)d_in[5];
  const float* ret_logit = (const float*)d_in[6];
  const float* theta = (const float*)d_in[7];
  const float* W_feat = (const float*)d_in[8];
  const float* b_feat = (const float*)d_in[9];
  const float* Wq = (const float*)d_in[10];
  const float* Wk = (const float*)d_in[11];
  const float* Wv = (const float*)d_in[12];
  const float* lnh_w = (const float*)d_in[13];
  const float* lnh_b = (const float*)d_in[14];
  const float* W1 = (const float*)d_in[15];
  const float* b1 = (const float*)d_in[16];
  const float* W2 = (const float*)d_in[17];
  const float* b2 = (const float*)d_in[18];
  const float* ln_w = (const float*)d_in[19];
  const float* ln_b = (const float*)d_in[20];

  // ---- workspace bump allocator (256B aligned) ----
  char* p = (char*)d_ws;
  auto alloc = [&](size_t bytes) {
    char* r = p;
    p += (bytes + 255) & ~(size_t)255;
    return r;
  };
  __hip_bfloat16* xb = (__hip_bfloat16*)alloc((size_t)Mm * Dd * 2);  // later: featb
  float* ur = (float*)alloc((size_t)Mm * NFf * 4);
  float* ui = (float*)alloc((size_t)Mm * NFf * 4);
  __hip_bfloat16* WTamp = (__hip_bfloat16*)alloc((size_t)NFf * Dd * 2);
  __hip_bfloat16* WTphi = (__hip_bfloat16*)alloc((size_t)NFf * Dd * 2);
  __hip_bfloat16* WTfeat = (__hip_bfloat16*)alloc((size_t)Dd * 3 * NFf * 2);
  __hip_bfloat16* WTq = (__hip_bfloat16*)alloc((size_t)Dd * Dd * 2);
  __hip_bfloat16* WTk = (__hip_bfloat16*)alloc((size_t)Dd * Dd * 2);
  __hip_bfloat16* WTv = (__hip_bfloat16*)alloc((size_t)Dd * Dd * 2);
  __hip_bfloat16* WT1 = (__hip_bfloat16*)alloc((size_t)Rr * Dd * 2);
  __hip_bfloat16* WT2 = (__hip_bfloat16*)alloc((size_t)Dd * Rr * 2);
  __hip_bfloat16* hb = (__hip_bfloat16*)alloc((size_t)Mm * Dd * 2);
  float* q = (float*)alloc((size_t)Mm * Dd * 4);  // later: yhb (bf16)
  float* k = (float*)alloc((size_t)Mm * Dd * 4);  // later: f1b (spans k+v)
  float* v = (float*)alloc((size_t)Mm * Dd * 4);
  float* y = (float*)alloc((size_t)Mm * Dd * 4);  // later: f2
  float* S = (float*)alloc((size_t)Bb * Hh * NCHK * 4096 * 4);
  float* Ksum = (float*)alloc((size_t)Bb * Hh * NCHK * 64 * 4);
  __hip_bfloat16* featb = xb;
  __hip_bfloat16* yhb = (__hip_bfloat16*)q;
  __hip_bfloat16* f1b = (__hip_bfloat16*)k;
  float* f2 = y;
  float* out = (float*)d_out;

  const dim3 blk(256);

  // 0: casts
  cast_x<<<dim3(Mm * Dd / 1024), blk, 0, stream>>>(x, xb);
  TCDesc tc;
  tc.src[0] = W_amp; tc.dst[0] = WTamp;
  tc.src[1] = W_phi; tc.dst[1] = WTphi;
  tc.src[2] = W_feat; tc.dst[2] = WTfeat;
  tc.src[3] = Wq; tc.dst[3] = WTq;
  tc.src[4] = Wk; tc.dst[4] = WTk;
  tc.src[5] = Wv; tc.dst[5] = WTv;
  tc.src[6] = W1; tc.dst[6] = WT1;
  tc.src[7] = W2; tc.dst[7] = WT2;
  transpose_cast_all<<<dim3(12544), blk, 0, stream>>>(tc);

  // 1-2: resonator input projections (fp32 out into ur/ui buffers pre-polar)
  gemm_mfma<EPI_SOFTPLUS, 0><<<dim3(NFf / 128, Mm / 128), blk, 0, stream>>>(
      (const short*)xb, (const short*)WTamp, b_amp, ur, nullptr, Mm, NFf, Dd);
  gemm_mfma<EPI_TANHPI, 0><<<dim3(NFf / 128, Mm / 128), blk, 0, stream>>>(
      (const short*)xb, (const short*)WTphi, b_phi, ui, nullptr, Mm, NFf, Dd);
  polar_kernel<<<dim3(Mm * NFf / 256), blk, 0, stream>>>(ur, ui);

  // 3: resonator scan -> feat (bf16); 8 blocks x 64 lanes (see kernel comment)
  resonator_scan<<<dim3(Bb * (NFf / 64)), dim3(64), 0, stream>>>(ur, ui, omega, ret_logit, theta, featb);

  // 4: feat projection -> h (bf16)
  gemm_mfma<EPI_RELU, 1><<<dim3(Dd / 128, Mm / 128), blk, 0, stream>>>(
      (const short*)featb, (const short*)WTfeat, b_feat, nullptr, hb, Mm, Dd, 3 * NFf);

  // 5-7: q,k,v projections (fp32 out)
  gemm_mfma<EPI_RELU, 0><<<dim3(Dd / 128, Mm / 128), blk, 0, stream>>>(
      (const short*)hb, (const short*)WTq, nullptr, q, nullptr, Mm, Dd, Dd);
  gemm_mfma<EPI_RELU, 0><<<dim3(Dd / 128, Mm / 128), blk, 0, stream>>>(
      (const short*)hb, (const short*)WTk, nullptr, k, nullptr, Mm, Dd, Dd);
  gemm_mfma<EPI_NONE, 0><<<dim3(Dd / 128, Mm / 128), blk, 0, stream>>>(
      (const short*)hb, (const short*)WTv, nullptr, v, nullptr, Mm, Dd, Dd);

  // 8: chunked causal linear attention
  attn_chunk_kv<<<dim3(Bb * Hh * NCHK), blk, 0, stream>>>(k, v, S, Ksum);
  attn_prefix<<<dim3(Bb * Hh), blk, 0, stream>>>(S, Ksum);
  attn_out<<<dim3(Bb * Hh * NCHK), blk, 0, stream>>>(q, k, v, S, Ksum, y);

  // 9: per-head layernorm -> bf16
  ln_head<<<dim3(Bb * Tt * Hh / 4), blk, 0, stream>>>(y, lnh_w, lnh_b, yhb);

  // 10-11: low-rank FFN
  gemm_mfma<EPI_RELU, 1><<<dim3(Rr / 128, Mm / 128), blk, 0, stream>>>(
      (const short*)yhb, (const short*)WT1, b1, nullptr, f1b, Mm, Rr, Dd);
  gemm_mfma<EPI_RELU, 0><<<dim3(Dd / 128, Mm / 128), blk, 0, stream>>>(
      (const short*)f1b, (const short*)WT2, b2, f2, nullptr, Mm, Dd, Rr);

  // 12: residual + final layernorm
  final_ln<<<dim3(Mm), blk, 0, stream>>>(x, f2, ln_w, ln_b, out);
}

// Round 5
// 337.885 us; speedup vs baseline: 5.6401x; 1.3671x over previous
//
#include <hip/hip_runtime.h>
#include <hip/hip_bf16.h>
#include <math.h>

#ifndef M_PI_F
#define M_PI_F 3.14159265358979323846f
#endif

static constexpr int Bb = 2, Tt = 1024, Dd = 1024, Hh = 16, DHh = 64, NFf = 256, Rr = 4096;
static constexpr int Mm = Bb * Tt;
static constexpr int CHK = 64, NCHK = Tt / CHK;  // attention chunking
static constexpr int QS = 3072;                  // fused qkv row stride

enum Epi { EPI_NONE = 0, EPI_RELU, EPI_SOFTPLUS, EPI_TANHPI, EPI_QKV, EPI_AMPPHI };

typedef __attribute__((ext_vector_type(8))) short bf16x8;
typedef __attribute__((ext_vector_type(4))) float f32x4;

// ---------------------------------------------------------------------------
// async global->LDS, 16B per lane. LDS dest is wave-uniform base; HW adds
// lane*16. Global address is per-lane.
// ---------------------------------------------------------------------------
__device__ inline void gload16(const short* g, short* l) {
  __builtin_amdgcn_global_load_lds(
      (const __attribute__((address_space(1))) unsigned int*)g,
      (__attribute__((address_space(3))) unsigned int*)l, 16, 0, 0);
}

// ---------------------------------------------------------------------------
// bf16 MFMA GEMM: C[M,N] = epi(A[M,K] @ BT[N,K]^T + bias)
// 128x128 tile, BK=64, 4 waves (2x2), each 64x64 via 4x4 frags of 16x16x32.
// - LDS XOR bank-swizzle (rule #21 both-sides involution): gload_lds dest
//   linear, global SOURCE pre-permuted (skk), ds_read applies same XOR.
//   Spreads the 16-lane same-column read over all 32 banks (was 4).
// - Bijective XCD swizzle (m204): consecutive intra-XCD blocks share by
//   (the A panel) -> A-panel L2 reuse per XCD.
// - SPLITK: blockIdx.z selects K-slice [z*1024,(z+1)*1024), writes fp32
//   partial at Cf + z*M*N (no epilogue).
// ---------------------------------------------------------------------------
template <int EPI, int OUTBF, int SPLITK>
__global__ __launch_bounds__(256) void gemm_mfma(const short* __restrict__ A,
                                                 const short* __restrict__ BT,
                                                 const float* __restrict__ bias,
                                                 const float* __restrict__ bias2,
                                                 float* __restrict__ Cf,
                                                 float* __restrict__ Cf2,
                                                 __hip_bfloat16* __restrict__ Cb,
                                                 int M, int N, int ldk) {
  __shared__ short lA[128 * 64];
  __shared__ short lB[128 * 64];
  const int tid = threadIdx.x;
  const int wid = tid >> 6, lane = tid & 63;

  // XCD-aware bijective block swizzle (grids here always have nwg % 8 == 0)
  const int nwg = gridDim.x * gridDim.y;
  const int wg = blockIdx.y * gridDim.x + blockIdx.x;
  const int qq = nwg >> 3, rr = nwg & 7;
  const int xcd = wg & 7, idx = wg >> 3;
  const int wg2 = (xcd < rr ? xcd * (qq + 1) : rr * (qq + 1) + (xcd - rr) * qq) + idx;
  const int bx = wg2 % gridDim.x, by = wg2 / gridDim.x;

  const int m0 = by * 128, n0 = bx * 128;
  const int wm = (wid >> 1) * 64, wn = (wid & 1) * 64;
  const int srow = lane >> 3;                            // row within 8-row slab
  const int skk = (((lane & 7) ^ (lane >> 3)) << 3);     // swizzled k offset (elems)

  int kstart = 0, klen = ldk;
  if (SPLITK) {
    kstart = blockIdx.z << 10;
    klen = 1024;
    Cf += (size_t)blockIdx.z * M * N;
  }

  f32x4 acc[4][4] = {};

  for (int k0 = kstart; k0 < kstart + klen; k0 += 64) {
#pragma unroll
    for (int si = 0; si < 4; ++si) {
      const int s = wid + si * 4;  // stage instruction index 0..15
      gload16(A + (size_t)(m0 + s * 8 + srow) * ldk + k0 + skk, &lA[s * 512]);
      gload16(BT + (size_t)(n0 + s * 8 + srow) * ldk + k0 + skk, &lB[s * 512]);
    }
    __syncthreads();  // drains vmcnt -> LDS tiles ready
#pragma unroll
    for (int kk = 0; kk < 2; ++kk) {
      const int krd = kk * 32 + (lane >> 4) * 8;
      const int rsel = lane & 15;
      const int kswz = krd ^ ((rsel & 7) << 3);  // same involution as store side
      bf16x8 af[4], bfr[4];
#pragma unroll
      for (int i = 0; i < 4; ++i) {
        af[i] = *(const bf16x8*)&lA[(wm + i * 16 + rsel) * 64 + kswz];
        bfr[i] = *(const bf16x8*)&lB[(wn + i * 16 + rsel) * 64 + kswz];
      }
#pragma unroll
      for (int i = 0; i < 4; ++i)
#pragma unroll
        for (int j = 0; j < 4; ++j)
          acc[i][j] = __builtin_amdgcn_mfma_f32_16x16x32_bf16(af[i], bfr[j], acc[i][j], 0, 0, 0);
    }
    __syncthreads();  // compute done before restage
  }

  const int crow = (lane >> 4) * 4;
  const int ccol = lane & 15;
#pragma unroll
  for (int j = 0; j < 4; ++j) {
    const int col = n0 + wn + j * 16 + ccol;
    float bv = 0.f;
    if (EPI == EPI_AMPPHI) {
      bv = (col < NFf) ? bias[col] : bias2[col - NFf];
    } else if (bias) {
      bv = bias[col];
    }
#pragma unroll
    for (int i = 0; i < 4; ++i) {
#pragma unroll
      for (int r = 0; r < 4; ++r) {
        float v = acc[i][j][r] + bv;
        const int row = m0 + wm + i * 16 + crow + r;
        if (EPI == EPI_AMPPHI) {
          if (col < NFf) {
            v = (v > 0.f) ? (v + log1pf(expf(-v))) : log1pf(expf(v));  // softplus
            Cf[(size_t)row * NFf + col] = v;
          } else {
            Cf2[(size_t)row * NFf + (col - NFf)] = M_PI_F * tanhf(v);
          }
        } else if (EPI == EPI_QKV) {
          Cf[(size_t)row * QS + col] = (col < 2048) ? fmaxf(v, 0.f) : v;
        } else {
          if (EPI == EPI_RELU) v = fmaxf(v, 0.f);
          const size_t off = (size_t)row * N + col;
          if (OUTBF)
            Cb[off] = __float2bfloat16(v);
          else
            Cf[off] = v;
        }
      }
    }
  }
}

// ---------------------------------------------------------------------------
// FFN2 split-K reduce: f2 = relu(sum_{ks<4} partial[ks] + b2)
// ---------------------------------------------------------------------------
__global__ __launch_bounds__(256) void reduce_ffn2(const float* __restrict__ part,
                                                   const float* __restrict__ b2,
                                                   float* __restrict__ f2) {
  const size_t base = ((size_t)blockIdx.x * 256 + threadIdx.x) * 4;
  const size_t MN = (size_t)Mm * Dd;
  float4 s = *(const float4*)&part[base];
#pragma unroll
  for (int ks = 1; ks < 4; ++ks) {
    const float4 pp = *(const float4*)&part[base + ks * MN];
    s.x += pp.x; s.y += pp.y; s.z += pp.z; s.w += pp.w;
  }
  const int col = (int)(base & (Dd - 1));
  const float4 bb = *(const float4*)&b2[col];
  float4 o;
  o.x = fmaxf(s.x + bb.x, 0.f);
  o.y = fmaxf(s.y + bb.y, 0.f);
  o.z = fmaxf(s.z + bb.z, 0.f);
  o.w = fmaxf(s.w + bb.w, 0.f);
  *(float4*)&f2[base] = o;
}

// ---------------------------------------------------------------------------
// Fused transpose-cast of all 8 weight matrices: W[K,N] f32 -> WT[N,K] bf16.
// ---------------------------------------------------------------------------
struct TCDesc {
  const float* src[8];
  __hip_bfloat16* dst[8];
};

__global__ __launch_bounds__(256) void transpose_cast_all(TCDesc d) {
  constexpr int KS[8] = {1024, 1024, 768, 1024, 1024, 1024, 1024, 4096};
  constexpr int NS[8] = {256, 256, 1024, 1024, 1024, 1024, 4096, 1024};
  constexpr int CUM[9] = {0, 256, 512, 1280, 2304, 3328, 4352, 8448, 12544};
  __shared__ float tile[32][33];
  const int bid = blockIdx.x;
  int w = 0;
#pragma unroll
  for (int i = 0; i < 8; ++i)
    if (bid >= CUM[i + 1]) w = i + 1;
  const int tlocal = bid - CUM[w];
  const int K = KS[w], N = NS[w];
  const int tilesN = N / 32;
  const int bk = (tlocal / tilesN) * 32, bn = (tlocal % tilesN) * 32;
  const float* W = d.src[w];
  __hip_bfloat16* WT = d.dst[w];
  const int tx = threadIdx.x & 31, ty = threadIdx.x >> 5;  // 32x8
#pragma unroll
  for (int r = 0; r < 32; r += 8) tile[ty + r][tx] = W[(size_t)(bk + ty + r) * N + bn + tx];
  __syncthreads();
#pragma unroll
  for (int r = 0; r < 32; r += 8)
    WT[(size_t)(bn + ty + r) * K + bk + tx] = __float2bfloat16(tile[tx][ty + r]);
}

// ---------------------------------------------------------------------------
// x: f32 -> bf16 cast (row-major, layout preserved)
// ---------------------------------------------------------------------------
__global__ __launch_bounds__(256) void cast_x(const float* __restrict__ x,
                                              __hip_bfloat16* __restrict__ xb) {
  const int i = (blockIdx.x * 256 + threadIdx.x) * 4;
  const float4 v = *(const float4*)&x[i];
  xb[i + 0] = __float2bfloat16(v.x);
  xb[i + 1] = __float2bfloat16(v.y);
  xb[i + 2] = __float2bfloat16(v.z);
  xb[i + 3] = __float2bfloat16(v.w);
}

// ---------------------------------------------------------------------------
// polar -> cartesian in place: (amp, phi) -> (amp*cos(phi), amp*sin(phi))
// ---------------------------------------------------------------------------
__global__ __launch_bounds__(256) void polar_kernel(float* __restrict__ a,
                                                    float* __restrict__ p) {
  const int i = blockIdx.x * 256 + threadIdx.x;
  const float am = a[i], ph = p[i];
  float s, c;
  sincosf(ph, &s, &c);
  a[i] = am * c;
  p[i] = am * s;
}

// ---------------------------------------------------------------------------
// Sequential complex resonator recurrence; writes feat bf16 [B,T,3*NF].
// 8 blocks x 64 lanes spread traffic over 8 CUs; register double-buffer
// (P=16) hides memory latency under the ALU chain (r3/r4 post-mortems).
// ---------------------------------------------------------------------------
static constexpr int RES_P = 16;

#define RES_LOAD(buf_r, buf_i, tg)                              \
  if ((tg) < Tt) {                                              \
    _Pragma("unroll") for (int i = 0; i < RES_P; ++i) {         \
      buf_r[i] = ur[bbase + (size_t)((tg) + i) * NFf];          \
      buf_i[i] = ui[bbase + (size_t)((tg) + i) * NFf];          \
    }                                                           \
  }

#define RES_STEP(buf_r, buf_i, tg)                              \
  _Pragma("unroll") for (int i = 0; i < RES_P; ++i) {           \
    const float pr = fmaf(ar, Xr, fmaf(-ai, Xi, buf_r[i]));     \
    const float pim = fmaf(ar, Xi, fmaf(ai, Xr, buf_i[i]));     \
    const float mag = __builtin_amdgcn_sqrtf(fmaf(pr, pr, pim * pim)); \
    const float g = __builtin_amdgcn_rcpf(1.f + __expf(th - mag));     \
    Xr = pr * g;                                                \
    Xi = pim * g;                                                \
    const size_t fb = ((size_t)b * Tt + (tg) + i) * (3 * NFf);  \
    featb[fb + f] = __float2bfloat16(Xr);                       \
    featb[fb + NFf + f] = __float2bfloat16(Xi);                 \
    featb[fb + 2 * NFf + f] = __float2bfloat16(mag * g);        \
  }

__global__ __launch_bounds__(64) void resonator_scan(const float* __restrict__ ur,
                                                     const float* __restrict__ ui,
                                                     const float* __restrict__ omega,
                                                     const float* __restrict__ ret_logit,
                                                     const float* __restrict__ theta,
                                                     __hip_bfloat16* __restrict__ featb) {
  const int b = blockIdx.x >> 2;                      // B = 2
  const int f = (blockIdx.x & 3) * 64 + threadIdx.x;  // 64-freq slice
  const float dec = 1.f / (1.f + __expf(-ret_logit[f]));
  float so, co;
  sincosf(omega[f], &so, &co);
  const float ar = dec * co, ai = dec * so;
  const float th = theta[f];
  const size_t bbase = (size_t)b * Tt * NFf + f;
  float Xr = 0.f, Xi = 0.f;
  float Ar[RES_P], Ai[RES_P], Br[RES_P], Bi[RES_P];
  RES_LOAD(Ar, Ai, 0);
  for (int t0 = 0; t0 < Tt; t0 += 2 * RES_P) {
    RES_LOAD(Br, Bi, t0 + RES_P);
    RES_STEP(Ar, Ai, t0);
    RES_LOAD(Ar, Ai, t0 + 2 * RES_P);
    RES_STEP(Br, Bi, t0 + RES_P);
  }
}

// ---------------------------------------------------------------------------
// Attention phase A: per-chunk KV outer-product sums and k-sums.
// q/k/v live in the fused qkv buffer (row stride QS=3072).
// ---------------------------------------------------------------------------
__global__ __launch_bounds__(256) void attn_chunk_kv(const float* __restrict__ k,
                                                     const float* __restrict__ v,
                                                     float* __restrict__ S,
                                                     float* __restrict__ Ksum) {
  __shared__ float Ks[64][68], Vs[64][68];
  const int g = blockIdx.x;
  const int j = g & (NCHK - 1), bh = g >> 4;
  const int b = bh >> 4, h = bh & (Hh - 1);
  const int tid = threadIdx.x;
  const size_t rowbase = (size_t)(b * Tt + j * CHK) * QS + h * DHh;
  for (int l = tid; l < 4096; l += 256) {
    const int s = l >> 6, d = l & 63;
    Ks[s][d] = k[rowbase + (size_t)s * QS + d];
    Vs[s][d] = v[rowbase + (size_t)s * QS + d];
  }
  __syncthreads();
  const int d0 = tid & 63, eb = tid >> 6, e0 = eb * 16;
  float4 acc4[4] = {};
  float ks = 0.f;
  for (int s = 0; s < 64; ++s) {
    const float kd = Ks[s][d0];
    ks += kd;
#pragma unroll
    for (int i = 0; i < 4; ++i) {
      const float4 v4 = *(const float4*)&Vs[s][e0 + 4 * i];
      acc4[i].x = fmaf(kd, v4.x, acc4[i].x);
      acc4[i].y = fmaf(kd, v4.y, acc4[i].y);
      acc4[i].z = fmaf(kd, v4.z, acc4[i].z);
      acc4[i].w = fmaf(kd, v4.w, acc4[i].w);
    }
  }
  float* Sg = S + (size_t)g * 4096 + (size_t)d0 * 64 + e0;
#pragma unroll
  for (int i = 0; i < 4; ++i) *(float4*)&Sg[4 * i] = acc4[i];
  if (eb == 0) Ksum[(size_t)g * 64 + d0] = ks;
}

// ---------------------------------------------------------------------------
// Attention phase B: in-place EXCLUSIVE prefix over the 16 chunks per (b,h).
// ---------------------------------------------------------------------------
__global__ __launch_bounds__(256) void attn_prefix(float* __restrict__ S,
                                                   float* __restrict__ Ksum) {
  const int bh = blockIdx.x;
  const int tid = threadIdx.x;
  for (int r = 0; r < 16; ++r) {
    const int de = r * 256 + tid;
    float run = 0.f;
    size_t p = (size_t)bh * (NCHK * 4096) + de;
    for (int j = 0; j < NCHK; ++j, p += 4096) {
      const float tmp = S[p];
      S[p] = run;
      run += tmp;
    }
  }
  if (tid < 64) {
    float run = 0.f;
    size_t p = (size_t)bh * (NCHK * 64) + tid;
    for (int j = 0; j < NCHK; ++j, p += 64) {
      const float tmp = Ksum[p];
      Ksum[p] = run;
      run += tmp;
    }
  }
}

// ---------------------------------------------------------------------------
// Attention phase C: per-chunk output (q/k/v strided QS; y is [B,T,H,DH]).
// ---------------------------------------------------------------------------
__global__ __launch_bounds__(256) void attn_out(const float* __restrict__ q,
                                                const float* __restrict__ k,
                                                const float* __restrict__ v,
                                                const float* __restrict__ S,
                                                const float* __restrict__ Ksum,
                                                float* __restrict__ y) {
  __shared__ float Qt[64][65];
  __shared__ float KVP[64][68];
  __shared__ float At[64][65];
  const int g = blockIdx.x;
  const int j = g & (NCHK - 1), bh = g >> 4;
  const int b = bh >> 4, h = bh & (Hh - 1);
  const int tid = threadIdx.x;
  const size_t rowbase = (size_t)(b * Tt + j * CHK) * QS + h * DHh;
  const size_t ybase = (((size_t)b * Tt + j * CHK) * Hh + h) * DHh;
  for (int l = tid; l < 4096; l += 256) {
    const int s = l >> 6, d = l & 63;
    Qt[d][s] = q[rowbase + (size_t)s * QS + d];
    KVP[s][d] = k[rowbase + (size_t)s * QS + d];
  }
  __syncthreads();
  const int t = tid >> 2, sg = tid & 3;
  const float* pk = Ksum + (size_t)g * 64;
  // --- stage 1: masked scores + denominator ---
  float adot[16] = {};
  float qpk = 0.f;
  for (int c = 0; c < 16; ++c) {
    const float q0 = Qt[4 * c + 0][t], q1 = Qt[4 * c + 1][t];
    const float q2 = Qt[4 * c + 2][t], q3 = Qt[4 * c + 3][t];
    const float4 pk4 = *(const float4*)&pk[4 * c];
    qpk = fmaf(q0, pk4.x, fmaf(q1, pk4.y, fmaf(q2, pk4.z, fmaf(q3, pk4.w, qpk))));
#pragma unroll
    for (int i = 0; i < 16; ++i) {
      const float4 k4 = *(const float4*)&KVP[sg * 16 + i][4 * c];
      adot[i] = fmaf(q0, k4.x, fmaf(q1, k4.y, fmaf(q2, k4.z, fmaf(q3, k4.w, adot[i]))));
    }
  }
  float rs = 0.f;
#pragma unroll
  for (int i = 0; i < 16; ++i) {
    if (sg * 16 + i > t) adot[i] = 0.f;
    rs += adot[i];
  }
  rs += __shfl_xor(rs, 1);
  rs += __shfl_xor(rs, 2);
  const float den = qpk + rs + 1e-6f;
  __syncthreads();  // all K reads complete
#pragma unroll
  for (int i = 0; i < 16; ++i) At[sg * 16 + i][t] = adot[i];
  for (int l = tid; l < 4096; l += 256) {  // overwrite K with V
    const int s = l >> 6, d = l & 63;
    KVP[s][d] = v[rowbase + (size_t)s * QS + d];
  }
  __syncthreads();
  // --- stage 2a: masked-score @ V ---
  const int e0 = sg * 16;
  float4 num[4] = {};
  for (int s = 0; s <= t; ++s) {
    const float av = At[s][t];
#pragma unroll
    for (int i = 0; i < 4; ++i) {
      const float4 v4 = *(const float4*)&KVP[s][e0 + 4 * i];
      num[i].x = fmaf(av, v4.x, num[i].x);
      num[i].y = fmaf(av, v4.y, num[i].y);
      num[i].z = fmaf(av, v4.z, num[i].z);
      num[i].w = fmaf(av, v4.w, num[i].w);
    }
  }
  __syncthreads();  // all V reads complete
  const float* Pg = S + (size_t)g * 4096;
  for (int l = tid; l < 4096; l += 256) KVP[l >> 6][l & 63] = Pg[l];
  __syncthreads();
  // --- stage 2b: Q @ P ---
  for (int d = 0; d < 64; ++d) {
    const float qd = Qt[d][t];
#pragma unroll
    for (int i = 0; i < 4; ++i) {
      const float4 p4 = *(const float4*)&KVP[d][e0 + 4 * i];
      num[i].x = fmaf(qd, p4.x, num[i].x);
      num[i].y = fmaf(qd, p4.y, num[i].y);
      num[i].z = fmaf(qd, p4.z, num[i].z);
      num[i].w = fmaf(qd, p4.w, num[i].w);
    }
  }
  const float inv = 1.f / den;
  float* yg = y + ybase + (size_t)t * (Hh * DHh) + e0;
#pragma unroll
  for (int i = 0; i < 4; ++i) {
    float4 o;
    o.x = num[i].x * inv;
    o.y = num[i].y * inv;
    o.z = num[i].z * inv;
    o.w = num[i].w * inv;
    *(float4*)&yg[4 * i] = o;
  }
}

// ---------------------------------------------------------------------------
// Per-head layernorm over DH=64, output bf16 [B,T,D].
// ---------------------------------------------------------------------------
__global__ __launch_bounds__(256) void ln_head(const float* __restrict__ y,
                                               const float* __restrict__ w,
                                               const float* __restrict__ bsh,
                                               __hip_bfloat16* __restrict__ out) {
  const int tid = threadIdx.x;
  const int e = tid & 63;
  const int r = blockIdx.x * 4 + (tid >> 6);
  const int h = r & (Hh - 1);
  const float val = y[(size_t)r * DHh + e];
  float s = val;
#pragma unroll
  for (int o = 1; o < 64; o <<= 1) s += __shfl_xor(s, o);
  const float mean = s * (1.f / 64.f);
  const float dv = val - mean;
  float s2 = dv * dv;
#pragma unroll
  for (int o = 1; o < 64; o <<= 1) s2 += __shfl_xor(s2, o);
  const float var = s2 * (1.f / 64.f);
  const float res = dv * rsqrtf(var + 1e-5f) * w[h * DHh + e] + bsh[h * DHh + e];
  out[(size_t)r * DHh + e] = __float2bfloat16(res);
}

// ---------------------------------------------------------------------------
// Residual + final layernorm over D=1024.
// ---------------------------------------------------------------------------
__global__ __launch_bounds__(256) void final_ln(const float* __restrict__ x,
                                                const float* __restrict__ f2,
                                                const float* __restrict__ w,
                                                const float* __restrict__ bb,
                                                float* __restrict__ out) {
  __shared__ float r1[4], r2[4];
  const int row = blockIdx.x;
  const int tid = threadIdx.x;
  const size_t off = (size_t)row * Dd + tid * 4;
  const float4 xa = *(const float4*)&x[off];
  const float4 fa = *(const float4*)&f2[off];
  float z[4] = {xa.x + fa.x, xa.y + fa.y, xa.z + fa.z, xa.w + fa.w};
  float s1 = z[0] + z[1] + z[2] + z[3];
  float s2 = z[0] * z[0] + z[1] * z[1] + z[2] * z[2] + z[3] * z[3];
#pragma unroll
  for (int o = 1; o < 64; o <<= 1) {
    s1 += __shfl_xor(s1, o);
    s2 += __shfl_xor(s2, o);
  }
  const int wid = tid >> 6;
  if ((tid & 63) == 0) {
    r1[wid] = s1;
    r2[wid] = s2;
  }
  __syncthreads();
  const float t1 = r1[0] + r1[1] + r1[2] + r1[3];
  const float t2 = r2[0] + r2[1] + r2[2] + r2[3];
  const float mu = t1 * (1.f / Dd);
  const float var = t2 * (1.f / Dd) - mu * mu;
  const float rsv = rsqrtf(var + 1e-5f);
  float4 o4;
  float* op = &o4.x;
#pragma unroll
  for (int jj = 0; jj < 4; ++jj) op[jj] = (z[jj] - mu) * rsv * w[tid * 4 + jj] + bb[tid * 4 + jj];
  *(float4*)&out[off] = o4;
}

// ---------------------------------------------------------------------------
extern "C" void kernel_launch(void* const* d_in, const int* in_sizes, int n_in,
                              void* d_out, int out_size, void* d_ws, size_t ws_size,
                              hipStream_t stream) {
  const float* x = (const float*)d_in[0];
  const float* W_amp = (const float*)d_in[1];
  const float* b_amp = (const float*)d_in[2];
  const float* W_phi = (const float*)d_in[3];
  const float* b_phi = (const float*)d_in[4];
  const float* omega = (const float*)d_in[5];
  const float* ret_logit = (const float*)d_in[6];
  const float* theta = (const float*)d_in[7];
  const float* W_feat = (const float*)d_in[8];
  const float* b_feat = (const float*)d_in[9];
  const float* Wq = (const float*)d_in[10];
  const float* Wk = (const float*)d_in[11];
  const float* Wv = (const float*)d_in[12];
  const float* lnh_w = (const float*)d_in[13];
  const float* lnh_b = (const float*)d_in[14];
  const float* W1 = (const float*)d_in[15];
  const float* b1 = (const float*)d_in[16];
  const float* W2 = (const float*)d_in[17];
  const float* b2 = (const float*)d_in[18];
  const float* ln_w = (const float*)d_in[19];
  const float* ln_b = (const float*)d_in[20];

  // ---- workspace bump allocator (256B aligned; all sizes are 256-multiples
  // so consecutive allocations are exactly contiguous — relied upon below) ----
  char* p = (char*)d_ws;
  auto alloc = [&](size_t bytes) {
    char* r = p;
    p += (bytes + 255) & ~(size_t)255;
    return r;
  };
  __hip_bfloat16* xb = (__hip_bfloat16*)alloc((size_t)Mm * Dd * 2);  // later: featb
  float* ur = (float*)alloc((size_t)Mm * NFf * 4);                   // later: partial[0..1]
  float* ui = (float*)alloc((size_t)Mm * NFf * 4);
  __hip_bfloat16* WTamp = (__hip_bfloat16*)alloc((size_t)NFf * Dd * 2);   // WTamp+WTphi contiguous (N=512)
  __hip_bfloat16* WTphi = (__hip_bfloat16*)alloc((size_t)NFf * Dd * 2);
  __hip_bfloat16* WTfeat = (__hip_bfloat16*)alloc((size_t)Dd * 3 * NFf * 2);
  __hip_bfloat16* WTq = (__hip_bfloat16*)alloc((size_t)Dd * Dd * 2);      // WTq+k+v contiguous (N=3072)
  __hip_bfloat16* WTk = (__hip_bfloat16*)alloc((size_t)Dd * Dd * 2);
  __hip_bfloat16* WTv = (__hip_bfloat16*)alloc((size_t)Dd * Dd * 2);
  __hip_bfloat16* WT1 = (__hip_bfloat16*)alloc((size_t)Rr * Dd * 2);
  __hip_bfloat16* WT2 = (__hip_bfloat16*)alloc((size_t)Dd * Rr * 2);
  __hip_bfloat16* hb = (__hip_bfloat16*)alloc((size_t)Mm * Dd * 2);
  float* qkv = (float*)alloc((size_t)Mm * QS * 4);  // 24 MB; later yhb (first 4MB) + f1b (last 16MB)
  float* y = (float*)alloc((size_t)Mm * Dd * 4);    // later: f2
  float* S = (float*)alloc((size_t)Bb * Hh * NCHK * 4096 * 4);
  float* Ksum = (float*)alloc((size_t)Bb * Hh * NCHK * 64 * 4);

  __hip_bfloat16* featb = xb;
  const float* q = qkv;
  const float* k = qkv + 1024;
  const float* v = qkv + 2048;
  __hip_bfloat16* yhb = (__hip_bfloat16*)qkv;                  // [M,1024] bf16 (4 MB)
  __hip_bfloat16* f1b = (__hip_bfloat16*)(qkv + (size_t)Mm * 1024);  // [M,4096] bf16 (16 MB)
  // FFN2 fp32 partials [4][M][1024] = 32 MB, overlaid on dead ur..WT1 (32.5 MB)
  float* partial = ur;
  float* f2 = y;
  float* out = (float*)d_out;

  const dim3 blk(256);

  // 0: casts
  cast_x<<<dim3(Mm * Dd / 1024), blk, 0, stream>>>(x, xb);
  TCDesc tc;
  tc.src[0] = W_amp; tc.dst[0] = WTamp;
  tc.src[1] = W_phi; tc.dst[1] = WTphi;
  tc.src[2] = W_feat; tc.dst[2] = WTfeat;
  tc.src[3] = Wq; tc.dst[3] = WTq;
  tc.src[4] = Wk; tc.dst[4] = WTk;
  tc.src[5] = Wv; tc.dst[5] = WTv;
  tc.src[6] = W1; tc.dst[6] = WT1;
  tc.src[7] = W2; tc.dst[7] = WT2;
  transpose_cast_all<<<dim3(12544), blk, 0, stream>>>(tc);

  // 1: fused amp/phi projection (N=512, dual epilogue -> ur, ui)
  gemm_mfma<EPI_AMPPHI, 0, 0><<<dim3(512 / 128, Mm / 128), blk, 0, stream>>>(
      (const short*)xb, (const short*)WTamp, b_amp, b_phi, ur, ui, nullptr, Mm, 512, Dd);
  polar_kernel<<<dim3(Mm * NFf / 256), blk, 0, stream>>>(ur, ui);

  // 2: resonator scan -> feat (bf16)
  resonator_scan<<<dim3(Bb * (NFf / 64)), dim3(64), 0, stream>>>(ur, ui, omega, ret_logit, theta, featb);

  // 3: feat projection -> h (bf16)
  gemm_mfma<EPI_RELU, 1, 0><<<dim3(Dd / 128, Mm / 128), blk, 0, stream>>>(
      (const short*)featb, (const short*)WTfeat, b_feat, nullptr, nullptr, nullptr, hb, Mm, Dd, 3 * NFf);

  // 4: fused q,k,v projection (N=3072 -> qkv buffer, relu on q,k only)
  gemm_mfma<EPI_QKV, 0, 0><<<dim3(QS / 128, Mm / 128), blk, 0, stream>>>(
      (const short*)hb, (const short*)WTq, nullptr, nullptr, qkv, nullptr, nullptr, Mm, QS, Dd);

  // 5: chunked causal linear attention
  attn_chunk_kv<<<dim3(Bb * Hh * NCHK), blk, 0, stream>>>(k, v, S, Ksum);
  attn_prefix<<<dim3(Bb * Hh), blk, 0, stream>>>(S, Ksum);
  attn_out<<<dim3(Bb * Hh * NCHK), blk, 0, stream>>>(q, k, v, S, Ksum, y);

  // 6: per-head layernorm -> bf16 (qkv dead; yhb overlays it)
  ln_head<<<dim3(Bb * Tt * Hh / 4), blk, 0, stream>>>(y, lnh_w, lnh_b, yhb);

  // 7: FFN1 -> f1b (bf16)
  gemm_mfma<EPI_RELU, 1, 0><<<dim3(Rr / 128, Mm / 128), blk, 0, stream>>>(
      (const short*)yhb, (const short*)WT1, b1, nullptr, nullptr, nullptr, f1b, Mm, Rr, Dd);

  // 8: FFN2 split-K=4 -> partials, then reduce(+bias+relu) -> f2
  gemm_mfma<EPI_NONE, 0, 1><<<dim3(Dd / 128, Mm / 128, 4), blk, 0, stream>>>(
      (const short*)f1b, (const short*)WT2, nullptr, nullptr, partial, nullptr, nullptr, Mm, Dd, Rr);
  reduce_ffn2<<<dim3(Mm * Dd / 1024), blk, 0, stream>>>(partial, b2, f2);

  // 9: residual + final layernorm
  final_ln<<<dim3(Mm), blk, 0, stream>>>(x, f2, ln_w, ln_b, out);
}